// Round 2
// baseline (276.837 us; speedup 1.0000x reference)
//
#include <hip/hip_runtime.h>
#include <hip/hip_bf16.h>
#include <stdint.h>

typedef unsigned short u16;
typedef unsigned int u32;

typedef __attribute__((ext_vector_type(8))) __bf16 bf16x8;
typedef __attribute__((ext_vector_type(4))) float f32x4;
typedef __attribute__((ext_vector_type(8))) u16 u16x8;

#define DIM 1024
#define SEQ 4096
#define NTOK 8192   // b*n
#define NBH 16      // b*h
#define NSLOT 96    // per-head split-K slots: qt<32 -> 1 chunk, qt>=32 -> 2 chunks (32 k-tiles each)

static __device__ __forceinline__ float bf2f(u16 u) {
    union { u32 u; float f; } c; c.u = ((u32)u) << 16; return c.f;
}
static __device__ __forceinline__ u16 f2bf(float f) {
    union { float f; u32 u; } c; c.f = f;
    u32 u = c.u;
    return (u16)((u + 0x7FFF + ((u >> 16) & 1)) >> 16);
}
static __device__ __forceinline__ u16 cvt_bf16(float f) {
    union { __bf16 b; u16 u; } c; c.b = (__bf16)f;  // RNE
    return c.u;
}
static __device__ __forceinline__ u32 pack_bf16(float lo, float hi) {
    return (u32)cvt_bf16(lo) | ((u32)cvt_bf16(hi) << 16);
}
static __device__ __forceinline__ f32x4 mfma_bf16(bf16x8 a, bf16x8 b, f32x4 c) {
    return __builtin_amdgcn_mfma_f32_16x16x32_bf16(a, b, c, 0, 0, 0);
}

typedef const __attribute__((address_space(1))) unsigned int* gptr_t;
typedef __attribute__((address_space(3))) unsigned int* lptr_t;

// ---------------- LayerNorm: one block per token row (fp32 in, bf16 out) ----
__global__ __launch_bounds__(256) void ln_kernel(const float* __restrict__ x,
                                                 const float* __restrict__ g,
                                                 const float* __restrict__ bta,
                                                 u16* __restrict__ xn) {
    int row = blockIdx.x;
    int tid = threadIdx.x;
    float4 v = ((const float4*)(x + (size_t)row * DIM))[tid];
    float f[4] = {v.x, v.y, v.z, v.w};
    float s = 0.f, s2 = 0.f;
#pragma unroll
    for (int i = 0; i < 4; i++) { s += f[i]; s2 += f[i] * f[i]; }
#pragma unroll
    for (int m = 1; m < 64; m <<= 1) { s += __shfl_xor(s, m); s2 += __shfl_xor(s2, m); }
    __shared__ float red[8];
    int w = tid >> 6;
    if ((tid & 63) == 0) { red[w * 2] = s; red[w * 2 + 1] = s2; }
    __syncthreads();
    s  = red[0] + red[2] + red[4] + red[6];
    s2 = red[1] + red[3] + red[5] + red[7];
    float mu = s * (1.f / DIM);
    float var = s2 * (1.f / DIM) - mu * mu;
    float rstd = rsqrtf(var + 1e-5f);
    u16 o[4];
#pragma unroll
    for (int i = 0; i < 4; i++) {
        int c = tid * 4 + i;
        o[i] = f2bf((f[i] - mu) * rstd * g[c] + bta[c]);
    }
    *(uint64_t*)(xn + (size_t)row * DIM + tid * 4) = *(uint64_t*)o;
}

// ---------------- transpose src[R][C] fp32 -> dst[C][R] bf16 ----------------
__global__ __launch_bounds__(256) void transpose_kernel(const float* __restrict__ src,
                                                        u16* __restrict__ dst,
                                                        int R, int C) {
    __shared__ float t[32][33];
    int lx = threadIdx.x & 31, ly = threadIdx.x >> 5;
    int c = blockIdx.x * 32 + lx;
#pragma unroll
    for (int i = 0; i < 32; i += 8)
        t[ly + i][lx] = src[(size_t)(blockIdx.y * 32 + ly + i) * C + c];
    __syncthreads();
    int rr = blockIdx.y * 32 + lx;
#pragma unroll
    for (int i = 0; i < 32; i += 8)
        dst[(size_t)(blockIdx.x * 32 + ly + i) * R + rr] = f2bf(t[lx][ly + i]);
}

// ---------------- 128x128 MFMA GEMM core (m97-style global_load_lds) -------
template <int K>
static __device__ __forceinline__ void gemm_core(const u16* __restrict__ A,
                                                 const u16* __restrict__ B,
                                                 int rowBase, int colBase,
                                                 u16* A_lds, u16* B_lds,
                                                 f32x4 acc[4][4]) {
    int tid = threadIdx.x;
    int lane = tid & 63;
    int l15 = lane & 15, q4 = lane >> 4;
    int w = tid >> 6;
    int wm = w >> 1, wn = w & 1;
#pragma unroll
    for (int mt = 0; mt < 4; mt++)
#pragma unroll
        for (int nt = 0; nt < 4; nt++) acc[mt][nt] = (f32x4){0.f, 0.f, 0.f, 0.f};

    char* Ab = (char*)A_lds;
    char* Bb = (char*)B_lds;

    for (int k0 = 0; k0 < K; k0 += 32) {
        __syncthreads();
#pragma unroll
        for (int i = 0; i < 2; i++) {
            int c = i * 256 + tid;
            int r = c >> 2;
            int piece = (c & 3) * 8;
            const u16* gA = A + (size_t)(rowBase + r) * K + k0 + piece;
            const u16* gB = B + (size_t)(colBase + r) * K + k0 + piece;
            unsigned ldsOff = (unsigned)(i * 4096 + w * 1024);  // wave-uniform
            __builtin_amdgcn_global_load_lds((gptr_t)gA, (lptr_t)(Ab + ldsOff), 16, 0, 0);
            __builtin_amdgcn_global_load_lds((gptr_t)gB, (lptr_t)(Bb + ldsOff), 16, 0, 0);
        }
        __syncthreads();
        bf16x8 a[4], b[4];
#pragma unroll
        for (int mt = 0; mt < 4; mt++)
            a[mt] = *(const bf16x8*)(A_lds + (wm * 64 + mt * 16 + l15) * 32 + q4 * 8);
#pragma unroll
        for (int nt = 0; nt < 4; nt++)
            b[nt] = *(const bf16x8*)(B_lds + (wn * 64 + nt * 16 + l15) * 32 + q4 * 8);
#pragma unroll
        for (int mt = 0; mt < 4; mt++)
#pragma unroll
            for (int nt = 0; nt < 4; nt++)
                acc[mt][nt] = mfma_bf16(a[mt], b[nt], acc[mt][nt]);
    }
}

// QKV GEMM: q gets softmax scale pre-folded; v stored transposed [bh][d][n]
__global__ __launch_bounds__(256) void gemm_qkv_kernel(const u16* __restrict__ xn,
                                                       const u16* __restrict__ wT,
                                                       u16* __restrict__ qb,
                                                       u16* __restrict__ kb,
                                                       u16* __restrict__ vbT) {
    __shared__ u16 A_lds[128 * 32];
    __shared__ u16 B_lds[128 * 32];
    f32x4 acc[4][4];
    gemm_core<1024>(xn, wT, blockIdx.x * 128, blockIdx.y * 128, A_lds, B_lds, acc);
    int lane = threadIdx.x & 63;
    int w = threadIdx.x >> 6;
    int wm = w >> 1, wn = w & 1;
    const float SC = 0.125f * 1.44269504f;  // scale * log2(e), folded into q
#pragma unroll
    for (int mt = 0; mt < 4; mt++) {
#pragma unroll
        for (int nt = 0; nt < 4; nt++) {
#pragma unroll
            for (int r = 0; r < 4; r++) {
                int m = blockIdx.x * 128 + wm * 64 + mt * 16 + (lane >> 4) * 4 + r;
                int n = blockIdx.y * 128 + wn * 64 + nt * 16 + (lane & 15);
                int piece = n >> 9;
                int c = n & 511;
                int h = c >> 6;
                int d = c & 63;
                int bi = m >> 12;
                int nn = m & 4095;
                int bh = bi * 8 + h;
                float av = acc[mt][nt][r];
                if (piece == 0)      qb[((size_t)(bh * SEQ + nn) << 6) + d] = f2bf(av * SC);
                else if (piece == 1) kb[((size_t)(bh * SEQ + nn) << 6) + d] = f2bf(av);
                else                 vbT[((size_t)(bh * 64 + d) << 12) + nn] = f2bf(av);
            }
        }
    }
}

// Out projection GEMM -> d_out fp32
__global__ __launch_bounds__(256) void gemm_out_kernel(const u16* __restrict__ aout,
                                                       const u16* __restrict__ wT,
                                                       float* __restrict__ out) {
    __shared__ u16 A_lds[128 * 32];
    __shared__ u16 B_lds[128 * 32];
    f32x4 acc[4][4];
    gemm_core<512>(aout, wT, blockIdx.x * 128, blockIdx.y * 128, A_lds, B_lds, acc);
    int lane = threadIdx.x & 63;
    int w = threadIdx.x >> 6;
    int wm = w >> 1, wn = w & 1;
#pragma unroll
    for (int mt = 0; mt < 4; mt++) {
#pragma unroll
        for (int nt = 0; nt < 4; nt++) {
#pragma unroll
            for (int r = 0; r < 4; r++) {
                int m = blockIdx.x * 128 + wm * 64 + mt * 16 + (lane >> 4) * 4 + r;
                int n = blockIdx.y * 128 + wn * 64 + nt * 16 + (lane & 15);
                out[(size_t)m * DIM + n] = acc[mt][nt][r];
            }
        }
    }
}

// ---------------- split-K causal flash attention (no-max softmax) ----------
// ONE WAVE PER BLOCK, 64 q-rows per wave (4 q-subtiles). No __syncthreads at
// all: K/V staged via global_load_lds (double-buffered, counted vmcnt) and
// consumed by the same wave; P is wave-private. Every K/V fragment read from
// LDS now feeds 4 MFMAs (one per q-subtile) -> 4x less LDS read traffic per
// unit of work vs the 4-wave/16q layout.
// LDS layout: linear [64][64] u16 with XOR swizzle col ^= (row&7)<<3 applied
// on the READ side; the global_load_lds SOURCE address is pre-swizzled so the
// linear DMA write lands data in swizzled position (rule #21 / m173 pattern).
// All read/write phases hit distinct bank quads -> conflict-free.

__global__ __launch_bounds__(64) void attn_partial_kernel(const u16* __restrict__ qb,
                                                          const u16* __restrict__ kb,
                                                          const u16* __restrict__ vbT,
                                                          u16* __restrict__ part,
                                                          float* __restrict__ lpart) {
    __shared__ u16 K_lds[2][4096];   // [buf][64 k-rows][64 d], swizzled
    __shared__ u16 V_lds[2][4096];   // [buf][64 d-rows][64 k], swizzled
    __shared__ u16 P_lds[4096];      // [64 q-rows][64 k], swizzled

    // XCD-aware swizzle (1536 = 8 * 192, bijective); big chunks first per XCD.
    int bid = blockIdx.x;
    int bs = (bid & 7) * 192 + (bid >> 3);
    int idx = NBH * NSLOT - 1 - bs;
    int bh = idx / NSLOT;
    int s  = idx - bh * NSLOT;
    int qt, ci;
    if (s < 32) { qt = s; ci = 0; }
    else        { int t = s - 32; qt = 32 + (t >> 1); ci = t & 1; }
    int kt0 = ci * 32;
    int kt1 = min(kt0 + 31, qt);

    int l = threadIdx.x;      // 0..63, one wave
    int l15 = l & 15, g = l >> 4;
    int swz = (l15 & 7) << 3; // read-side XOR (u16 units, 16B granules)

    const u16* Kp0 = kb + (size_t)bh * SEQ * 64;
    const u16* VTp = vbT + (size_t)bh * 64 * SEQ;
    const u16* Qp  = qb + ((size_t)bh * SEQ + (size_t)qt * 64) * 64;

    // Q fragments (B-operand) for all 4 q-subtiles, straight from global.
    bf16x8 bQ[4][2];
#pragma unroll
    for (int qs = 0; qs < 4; qs++) {
        const u16* qp = Qp + (qs * 16 + l15) * 64 + g * 8;
        bQ[qs][0] = *(const bf16x8*)qp;
        bQ[qs][1] = *(const bf16x8*)(qp + 32);
    }

    // Pre-swizzled DMA source mapping: LDS linear slot (op i, lane l) is
    // row r = i*8 + (l>>3), physical col (l&7)*8; the element that belongs
    // there is logical col ((l&7) ^ (l>>3)) * 8 of row r.
    int srow = l >> 3;                 // row within 8-row op group
    int scol = ((l & 7) ^ srow) * 8;   // pre-swizzled logical col (u16)

    // Prologue: DMA tile kt0 into buffer 0.
    {
        const u16* Kt = Kp0 + (size_t)kt0 * 4096;
#pragma unroll
        for (int i = 0; i < 8; i++) {
            __builtin_amdgcn_global_load_lds((gptr_t)(Kt + (i * 8 + srow) * 64 + scol),
                                             (lptr_t)((char*)&K_lds[0][0] + i * 1024), 16, 0, 0);
            __builtin_amdgcn_global_load_lds((gptr_t)(VTp + (size_t)(i * 8 + srow) * SEQ + kt0 * 64 + scol),
                                             (lptr_t)((char*)&V_lds[0][0] + i * 1024), 16, 0, 0);
        }
    }

    f32x4 Oacc[4][4];
    f32x4 l_acc[4];
#pragma unroll
    for (int qs = 0; qs < 4; qs++) {
        l_acc[qs] = (f32x4){0.f, 0.f, 0.f, 0.f};
#pragma unroll
        for (int vt = 0; vt < 4; vt++) Oacc[qs][vt] = (f32x4){0.f, 0.f, 0.f, 0.f};
    }

    const __bf16 one_bf = (__bf16)1.0f;
    bf16x8 vones = {one_bf, one_bf, one_bf, one_bf, one_bf, one_bf, one_bf, one_bf};

    int rd0 = (g * 8) ^ swz;        // read col for low k/d half
    int rd1 = (32 + g * 8) ^ swz;   // read col for high half

    int cur = 0;
    for (int kt = kt0; kt <= kt1; kt++) {
        // Issue next tile's DMA into the other buffer, then wait for the 16
        // oldest (current tile) only: loads stay in flight across compute.
        if (kt < kt1) {
            const u16* Kt = Kp0 + (size_t)(kt + 1) * 4096;
            char* kd = (char*)&K_lds[cur ^ 1][0];
            char* vd = (char*)&V_lds[cur ^ 1][0];
#pragma unroll
            for (int i = 0; i < 8; i++) {
                __builtin_amdgcn_global_load_lds((gptr_t)(Kt + (i * 8 + srow) * 64 + scol),
                                                 (lptr_t)(kd + i * 1024), 16, 0, 0);
                __builtin_amdgcn_global_load_lds((gptr_t)(VTp + (size_t)(i * 8 + srow) * SEQ + (kt + 1) * 64 + scol),
                                                 (lptr_t)(vd + i * 1024), 16, 0, 0);
            }
            asm volatile("s_waitcnt vmcnt(16)" ::: "memory");
        } else {
            asm volatile("s_waitcnt vmcnt(0)" ::: "memory");
        }
        __builtin_amdgcn_sched_barrier(0);

        const u16* KL = &K_lds[cur][0];
        const u16* VL = &V_lds[cur][0];

        // K fragments once, reused by all 4 q-subtiles.
        bf16x8 ka[4][2];
#pragma unroll
        for (int mt = 0; mt < 4; mt++) {
            int row = mt * 16 + l15;
            ka[mt][0] = *(const bf16x8*)(KL + row * 64 + rd0);
            ka[mt][1] = *(const bf16x8*)(KL + row * 64 + rd1);
        }

        // QK^T (swapped) + exp2 + packed P write, per q-subtile.
#pragma unroll
        for (int qs = 0; qs < 4; qs++) {
            f32x4 sv[4];
#pragma unroll
            for (int mt = 0; mt < 4; mt++) {
                f32x4 z = (f32x4){0.f, 0.f, 0.f, 0.f};
                z = mfma_bf16(ka[mt][0], bQ[qs][0], z);
                z = mfma_bf16(ka[mt][1], bQ[qs][1], z);
                sv[mt] = z;
            }
            int prow = qs * 16 + l15;
            u16* pb = P_lds + prow * 64;
            if (kt != qt) {
#pragma unroll
                for (int mt = 0; mt < 4; mt++) {
                    uint2 t;
                    t.x = pack_bf16(__builtin_amdgcn_exp2f(sv[mt][0]),
                                    __builtin_amdgcn_exp2f(sv[mt][1]));
                    t.y = pack_bf16(__builtin_amdgcn_exp2f(sv[mt][2]),
                                    __builtin_amdgcn_exp2f(sv[mt][3]));
                    *(uint2*)(pb + ((mt * 16 + g * 4) ^ swz)) = t;
                }
            } else {
                int qg = qs * 16 + l15;
#pragma unroll
                for (int mt = 0; mt < 4; mt++) {
                    float p[4];
#pragma unroll
                    for (int r = 0; r < 4; r++) {
                        int kg = mt * 16 + g * 4 + r;
                        p[r] = (kg <= qg) ? __builtin_amdgcn_exp2f(sv[mt][r]) : 0.f;
                    }
                    uint2 t;
                    t.x = pack_bf16(p[0], p[1]);
                    t.y = pack_bf16(p[2], p[3]);
                    *(uint2*)(pb + ((mt * 16 + g * 4) ^ swz)) = t;
                }
            }
        }

        // P fragments (A-operand) + denominator via ones-column MFMA.
        bf16x8 aP[4][2];
#pragma unroll
        for (int qs = 0; qs < 4; qs++) {
            int prow = qs * 16 + l15;
            aP[qs][0] = *(const bf16x8*)(P_lds + prow * 64 + rd0);
            aP[qs][1] = *(const bf16x8*)(P_lds + prow * 64 + rd1);
            l_acc[qs] = mfma_bf16(aP[qs][0], vones, l_acc[qs]);
            l_acc[qs] = mfma_bf16(aP[qs][1], vones, l_acc[qs]);
        }

        // PV: each V fragment read once, feeds all 4 q-subtiles.
#pragma unroll
        for (int vt = 0; vt < 4; vt++) {
            int vrow = vt * 16 + l15;
            bf16x8 bV0 = *(const bf16x8*)(VL + vrow * 64 + rd0);
            bf16x8 bV1 = *(const bf16x8*)(VL + vrow * 64 + rd1);
#pragma unroll
            for (int qs = 0; qs < 4; qs++) {
                Oacc[qs][vt] = mfma_bf16(aP[qs][0], bV0, Oacc[qs][vt]);
                Oacc[qs][vt] = mfma_bf16(aP[qs][1], bV1, Oacc[qs][vt]);
            }
        }

        cur ^= 1;
    }

    // write partials: Onum (bf16) + l (fp32); slot == idx
    // Oacc layout: O[q = qs*16 + g*4 + r][d = vt*16 + l15]
    u16* po = part + (size_t)idx * 4096;
#pragma unroll
    for (int qs = 0; qs < 4; qs++) {
#pragma unroll
        for (int vt = 0; vt < 4; vt++)
#pragma unroll
            for (int r = 0; r < 4; r++) {
                int q = qs * 16 + g * 4 + r;
                int d = vt * 16 + l15;
                po[q * 64 + d] = f2bf(Oacc[qs][vt][r]);
            }
        if (l15 == 0) {
#pragma unroll
            for (int r = 0; r < 4; r++)
                lpart[(size_t)idx * 64 + qs * 16 + g * 4 + r] = l_acc[qs][r];
        }
    }
}

// combine partials -> aout bf16 [8192][512]
__global__ __launch_bounds__(256) void attn_combine_kernel(const u16* __restrict__ part,
                                                           const float* __restrict__ lpart,
                                                           u16* __restrict__ aout) {
    int bid = blockIdx.x;          // 16*64
    int bh = bid >> 6;
    int qt = bid & 63;
    int nc = 1 + (qt >> 5);
    int sb = bh * NSLOT + (qt < 32 ? qt : 32 + (qt - 32) * 2);

    int t = threadIdx.x;
    int q = t >> 2;
    int dg = (t & 3) * 16;

    float acc[16];
#pragma unroll
    for (int j = 0; j < 16; j++) acc[j] = 0.f;
    float ll = 0.f;
    for (int ci = 0; ci < nc; ci++) {
        const u16* pp = part + (size_t)(sb + ci) * 4096 + q * 64 + dg;
        u16x8 v0 = *(const u16x8*)pp;
        u16x8 v1 = *(const u16x8*)(pp + 8);
#pragma unroll
        for (int j = 0; j < 8; j++) { acc[j] += bf2f(v0[j]); acc[8 + j] += bf2f(v1[j]); }
        ll += lpart[(size_t)(sb + ci) * 64 + q];
    }
    float inv = 1.f / (ll + 1e-10f);
    int b = bh >> 3, h = bh & 7;
    size_t row = (size_t)(b * SEQ + qt * 64 + q);
    u16 o[16];
#pragma unroll
    for (int j = 0; j < 16; j++) o[j] = f2bf(acc[j] * inv);
    u16* dst = aout + row * 512 + h * 64 + dg;
    *(u16x8*)dst = *(u16x8*)o;
    *(u16x8*)(dst + 8) = *(u16x8*)(o + 8);
}

extern "C" void kernel_launch(void* const* d_in, const int* in_sizes, int n_in,
                              void* d_out, int out_size, void* d_ws, size_t ws_size,
                              hipStream_t stream) {
    const float* x    = (const float*)d_in[0];
    const float* g    = (const float*)d_in[1];
    const float* bta  = (const float*)d_in[2];
    const float* wqkv = (const float*)d_in[3];
    const float* wout = (const float*)d_in[4];
    float* out = (float*)d_out;

    char* ws = (char*)d_ws;
    size_t off = 0;
    auto alloc = [&](size_t bytes) {
        void* p = ws + off;
        off += (bytes + 255) & ~(size_t)255;
        return p;
    };
    // Footprint kept <= 46.1 MB (round-4's 54.6 MB is known-good; round-5's
    // 76 MB overran d_ws and corrupted neighboring allocations during timing).
    u16* xn    = (u16*)alloc((size_t)NTOK * DIM * 2);       // 16.78 MB; dead after gemm_qkv
    u16* wqkvT = (u16*)alloc((size_t)1536 * 1024 * 2);      //  3.15 MB
    u16* woutT = (u16*)alloc((size_t)1024 * 512 * 2);       //  1.05 MB
    u16* qb    = (u16*)alloc((size_t)NBH * SEQ * 64 * 2);   //  8.39 MB; dead after attn_partial
    u16* kb    = (u16*)alloc((size_t)NBH * SEQ * 64 * 2);   //  8.39 MB
    u16* vbT   = (u16*)alloc((size_t)NBH * SEQ * 64 * 2);   //  8.39 MB
    // Aliases (lifetimes disjoint by stream order, valid on every replay):
    u16* part  = xn;                                        // 12.58 MB into xn region
    float* lpart = (float*)(xn + (size_t)NBH * NSLOT * 4096); // +0.39 MB, still < xn's 16.78 MB
    u16* aout  = qb;                                        // combine writes after attn_partial reads qb

    ln_kernel<<<NTOK, 256, 0, stream>>>(x, g, bta, xn);
    transpose_kernel<<<dim3(1536 / 32, 1024 / 32), 256, 0, stream>>>(wqkv, wqkvT, 1024, 1536);
    transpose_kernel<<<dim3(1024 / 32, 512 / 32), 256, 0, stream>>>(wout, woutT, 512, 1024);
    gemm_qkv_kernel<<<dim3(64, 12), 256, 0, stream>>>(xn, wqkvT, qb, kb, vbT);
    attn_partial_kernel<<<NBH * NSLOT, 64, 0, stream>>>(qb, kb, vbT, part, lpart);
    attn_combine_kernel<<<NBH * 64, 256, 0, stream>>>(part, lpart, aout);
    gemm_out_kernel<<<dim3(64, 8), 256, 0, stream>>>(aout, woutT, out);
}

// Round 5
// 261.269 us; speedup vs baseline: 1.0596x; 1.0596x over previous
//
#include <hip/hip_runtime.h>
#include <hip/hip_bf16.h>
#include <stdint.h>

typedef unsigned short u16;
typedef unsigned int u32;

typedef __attribute__((ext_vector_type(8))) __bf16 bf16x8;
typedef __attribute__((ext_vector_type(4))) float f32x4;
typedef __attribute__((ext_vector_type(8))) u16 u16x8;

#define DIM 1024
#define SEQ 4096
#define NTOK 8192   // b*n
#define NBH 16      // b*h
#define NSLOT 24    // per-head split-K slots over 256-row q-blocks (j<8: 1 chunk, j>=8: 2)

static __device__ __forceinline__ float bf2f(u16 u) {
    union { u32 u; float f; } c; c.u = ((u32)u) << 16; return c.f;
}
static __device__ __forceinline__ u16 f2bf(float f) {
    union { float f; u32 u; } c; c.f = f;
    u32 u = c.u;
    return (u16)((u + 0x7FFF + ((u >> 16) & 1)) >> 16);
}
static __device__ __forceinline__ u16 cvt_bf16(float f) {
    union { __bf16 b; u16 u; } c; c.b = (__bf16)f;  // RNE
    return c.u;
}
static __device__ __forceinline__ u32 pack_bf16(float lo, float hi) {
    return (u32)cvt_bf16(lo) | ((u32)cvt_bf16(hi) << 16);
}
static __device__ __forceinline__ f32x4 mfma_bf16(bf16x8 a, bf16x8 b, f32x4 c) {
    return __builtin_amdgcn_mfma_f32_16x16x32_bf16(a, b, c, 0, 0, 0);
}

typedef const __attribute__((address_space(1))) unsigned int* gptr_t;
typedef __attribute__((address_space(3))) unsigned int* lptr_t;

// ---------------- LayerNorm: one block per token row (fp32 in, bf16 out) ----
__global__ __launch_bounds__(256) void ln_kernel(const float* __restrict__ x,
                                                 const float* __restrict__ g,
                                                 const float* __restrict__ bta,
                                                 u16* __restrict__ xn) {
    int row = blockIdx.x;
    int tid = threadIdx.x;
    float4 v = ((const float4*)(x + (size_t)row * DIM))[tid];
    float f[4] = {v.x, v.y, v.z, v.w};
    float s = 0.f, s2 = 0.f;
#pragma unroll
    for (int i = 0; i < 4; i++) { s += f[i]; s2 += f[i] * f[i]; }
#pragma unroll
    for (int m = 1; m < 64; m <<= 1) { s += __shfl_xor(s, m); s2 += __shfl_xor(s2, m); }
    __shared__ float red[8];
    int w = tid >> 6;
    if ((tid & 63) == 0) { red[w * 2] = s; red[w * 2 + 1] = s2; }
    __syncthreads();
    s  = red[0] + red[2] + red[4] + red[6];
    s2 = red[1] + red[3] + red[5] + red[7];
    float mu = s * (1.f / DIM);
    float var = s2 * (1.f / DIM) - mu * mu;
    float rstd = rsqrtf(var + 1e-5f);
    u16 o[4];
#pragma unroll
    for (int i = 0; i < 4; i++) {
        int c = tid * 4 + i;
        o[i] = f2bf((f[i] - mu) * rstd * g[c] + bta[c]);
    }
    *(uint64_t*)(xn + (size_t)row * DIM + tid * 4) = *(uint64_t*)o;
}

// ---------------- transpose src[R][C] fp32 -> dst[C][R] bf16 ----------------
__global__ __launch_bounds__(256) void transpose_kernel(const float* __restrict__ src,
                                                        u16* __restrict__ dst,
                                                        int R, int C) {
    __shared__ float t[32][33];
    int lx = threadIdx.x & 31, ly = threadIdx.x >> 5;
    int c = blockIdx.x * 32 + lx;
#pragma unroll
    for (int i = 0; i < 32; i += 8)
        t[ly + i][lx] = src[(size_t)(blockIdx.y * 32 + ly + i) * C + c];
    __syncthreads();
    int rr = blockIdx.y * 32 + lx;
#pragma unroll
    for (int i = 0; i < 32; i += 8)
        dst[(size_t)(blockIdx.x * 32 + ly + i) * R + rr] = f2bf(t[lx][ly + i]);
}

// ---------------- 128x128 MFMA GEMM core (m97-style global_load_lds) -------
template <int K>
static __device__ __forceinline__ void gemm_core(const u16* __restrict__ A,
                                                 const u16* __restrict__ B,
                                                 int rowBase, int colBase,
                                                 u16* A_lds, u16* B_lds,
                                                 f32x4 acc[4][4]) {
    int tid = threadIdx.x;
    int lane = tid & 63;
    int l15 = lane & 15, q4 = lane >> 4;
    int w = tid >> 6;
    int wm = w >> 1, wn = w & 1;
#pragma unroll
    for (int mt = 0; mt < 4; mt++)
#pragma unroll
        for (int nt = 0; nt < 4; nt++) acc[mt][nt] = (f32x4){0.f, 0.f, 0.f, 0.f};

    char* Ab = (char*)A_lds;
    char* Bb = (char*)B_lds;

    for (int k0 = 0; k0 < K; k0 += 32) {
        __syncthreads();
#pragma unroll
        for (int i = 0; i < 2; i++) {
            int c = i * 256 + tid;
            int r = c >> 2;
            int piece = (c & 3) * 8;
            const u16* gA = A + (size_t)(rowBase + r) * K + k0 + piece;
            const u16* gB = B + (size_t)(colBase + r) * K + k0 + piece;
            unsigned ldsOff = (unsigned)(i * 4096 + w * 1024);  // wave-uniform
            __builtin_amdgcn_global_load_lds((gptr_t)gA, (lptr_t)(Ab + ldsOff), 16, 0, 0);
            __builtin_amdgcn_global_load_lds((gptr_t)gB, (lptr_t)(Bb + ldsOff), 16, 0, 0);
        }
        __syncthreads();
        bf16x8 a[4], b[4];
#pragma unroll
        for (int mt = 0; mt < 4; mt++)
            a[mt] = *(const bf16x8*)(A_lds + (wm * 64 + mt * 16 + l15) * 32 + q4 * 8);
#pragma unroll
        for (int nt = 0; nt < 4; nt++)
            b[nt] = *(const bf16x8*)(B_lds + (wn * 64 + nt * 16 + l15) * 32 + q4 * 8);
#pragma unroll
        for (int mt = 0; mt < 4; mt++)
#pragma unroll
            for (int nt = 0; nt < 4; nt++)
                acc[mt][nt] = mfma_bf16(a[mt], b[nt], acc[mt][nt]);
    }
}

// QKV GEMM: q gets softmax scale pre-folded; v stored transposed [bh][d][n]
__global__ __launch_bounds__(256) void gemm_qkv_kernel(const u16* __restrict__ xn,
                                                       const u16* __restrict__ wT,
                                                       u16* __restrict__ qb,
                                                       u16* __restrict__ kb,
                                                       u16* __restrict__ vbT) {
    __shared__ u16 A_lds[128 * 32];
    __shared__ u16 B_lds[128 * 32];
    f32x4 acc[4][4];
    gemm_core<1024>(xn, wT, blockIdx.x * 128, blockIdx.y * 128, A_lds, B_lds, acc);
    int lane = threadIdx.x & 63;
    int w = threadIdx.x >> 6;
    int wm = w >> 1, wn = w & 1;
    const float SC = 0.125f * 1.44269504f;  // scale * log2(e), folded into q
#pragma unroll
    for (int mt = 0; mt < 4; mt++) {
#pragma unroll
        for (int nt = 0; nt < 4; nt++) {
#pragma unroll
            for (int r = 0; r < 4; r++) {
                int m = blockIdx.x * 128 + wm * 64 + mt * 16 + (lane >> 4) * 4 + r;
                int n = blockIdx.y * 128 + wn * 64 + nt * 16 + (lane & 15);
                int piece = n >> 9;
                int c = n & 511;
                int h = c >> 6;
                int d = c & 63;
                int bi = m >> 12;
                int nn = m & 4095;
                int bh = bi * 8 + h;
                float av = acc[mt][nt][r];
                if (piece == 0)      qb[((size_t)(bh * SEQ + nn) << 6) + d] = f2bf(av * SC);
                else if (piece == 1) kb[((size_t)(bh * SEQ + nn) << 6) + d] = f2bf(av);
                else                 vbT[((size_t)(bh * 64 + d) << 12) + nn] = f2bf(av);
            }
        }
    }
}

// Out projection GEMM -> d_out fp32
__global__ __launch_bounds__(256) void gemm_out_kernel(const u16* __restrict__ aout,
                                                       const u16* __restrict__ wT,
                                                       float* __restrict__ out) {
    __shared__ u16 A_lds[128 * 32];
    __shared__ u16 B_lds[128 * 32];
    f32x4 acc[4][4];
    gemm_core<512>(aout, wT, blockIdx.x * 128, blockIdx.y * 128, A_lds, B_lds, acc);
    int lane = threadIdx.x & 63;
    int w = threadIdx.x >> 6;
    int wm = w >> 1, wn = w & 1;
#pragma unroll
    for (int mt = 0; mt < 4; mt++) {
#pragma unroll
        for (int nt = 0; nt < 4; nt++) {
#pragma unroll
            for (int r = 0; r < 4; r++) {
                int m = blockIdx.x * 128 + wm * 64 + mt * 16 + (lane >> 4) * 4 + r;
                int n = blockIdx.y * 128 + wn * 64 + nt * 16 + (lane & 15);
                out[(size_t)m * DIM + n] = acc[mt][nt][r];
            }
        }
    }
}

// ---------------- split-K causal flash attention (no-max softmax) ----------
// Block = 4 waves, 256 q-rows (wave w owns rows w*64..w*64+63 of q-block j).
// Each wave reads a K/V LDS fragment once and feeds it to 4 q-subtiles ->
// 4x fragment reuse vs the 64q/4-wave layout, at 8-12 waves/CU.
// Staging mechanics are the round-1-proven ones: per-thread u16x8 register
// prefetch -> swizzled ds_write_b128 (per-lane writes CAN be swizzled, no
// global_load_lds wave-uniform-dest constraint), single K/V buffer, two
// __syncthreads per k-tile. Next-tile loads are issued AFTER barrier 2 so
// they overlap the whole compute phase; the vmcnt(0) drain inside the next
// iteration's barrier 1 finds them already landed.
// LDS XOR swizzle: logical 16B-granule ggr of row r lives at physical
// granule ggr ^ (r&7); reads use col ^ ((row&7)<<3). All b128 phases reduce
// to the stride-1 baseline bank pattern -> conflict-free.
// Slots: j<8 -> 1 chunk [0, 4j+3]; j>=8 -> 2 chunks [0,2j+1], [2j+2,4j+3].

__global__ __launch_bounds__(256) void attn_partial_kernel(const u16* __restrict__ qb,
                                                           const u16* __restrict__ kb,
                                                           const u16* __restrict__ vbT,
                                                           u16* __restrict__ part,
                                                           float* __restrict__ lpart) {
    __shared__ u16 K_lds[4096];      // [64 k-rows][64 d], swizzled    8KB
    __shared__ u16 V_lds[4096];      // [64 d-rows][64 k], swizzled    8KB
    __shared__ u16 P_lds[4][1024];   // per-wave 16x64 scratch         8KB

    // XCD-aware bijective swizzle (384 = 8 * 48): each XCD gets 2 bh of K/V
    // (~2MB) hot in its private L2; big chunks dispatch first per XCD.
    int bid = blockIdx.x;
    int bs = (bid & 7) * 48 + (bid >> 3);
    int idx = NBH * NSLOT - 1 - bs;
    int bh = idx / NSLOT;
    int s  = idx - bh * NSLOT;
    int j, ci;
    if (s < 8) { j = s; ci = 0; }
    else       { int t = s - 8; j = 8 + (t >> 1); ci = t & 1; }
    int kt0, kt1;
    if (ci == 0) { kt0 = 0;         kt1 = (j < 8) ? (4 * j + 3) : (2 * j + 1); }
    else         { kt0 = 2 * j + 2; kt1 = 4 * j + 3; }

    int tid = threadIdx.x;
    int lane = tid & 63;
    int l15 = lane & 15, g = lane >> 4;
    int w = tid >> 6;
    int swz = (l15 & 7) << 3;       // read-side XOR (u16 units, 16B granules)
    int rd0 = (g * 8) ^ swz;
    int rd1 = (32 + g * 8) ^ swz;

    const u16* Kp0 = kb + (size_t)bh * SEQ * 64;
    const u16* VTp = vbT + (size_t)bh * 64 * SEQ;
    const u16* Qp  = qb + ((size_t)bh * SEQ + (size_t)j * 256 + w * 64) * 64;

    // Q fragments (B-operand) for this wave's 64 q-rows, straight from global.
    bf16x8 bQ[4][2];
#pragma unroll
    for (int qs = 0; qs < 4; qs++) {
        const u16* qp = Qp + (qs * 16 + l15) * 64 + g * 8;
        bQ[qs][0] = *(const bf16x8*)qp;
        bQ[qs][1] = *(const bf16x8*)(qp + 32);
    }

    int qt_w = j * 4 + w;           // this wave's diagonal k-tile index

    // Staging: 512 granules (16B) per 64x64 tile, 2 per thread.
    int c0 = tid, c1 = tid + 256;
    int r0 = c0 >> 3, g0 = c0 & 7;
    int r1 = c1 >> 3, g1 = c1 & 7;
    int wc0 = r0 * 64 + ((g0 ^ (r0 & 7)) * 8);   // swizzled LDS u16 index
    int wc1 = r1 * 64 + ((g1 ^ (r1 & 7)) * 8);

    // Prefetch tile kt0 into registers.
    u16x8 krA0, krA1, vrA0, vrA1;
    {
        const u16* Kt = Kp0 + (size_t)kt0 * 4096;
        krA0 = *(const u16x8*)(Kt + r0 * 64 + g0 * 8);
        krA1 = *(const u16x8*)(Kt + r1 * 64 + g1 * 8);
        vrA0 = *(const u16x8*)(VTp + (size_t)r0 * SEQ + kt0 * 64 + g0 * 8);
        vrA1 = *(const u16x8*)(VTp + (size_t)r1 * SEQ + kt0 * 64 + g1 * 8);
    }

    f32x4 Oacc[4][4];
    f32x4 l_acc4[4];
#pragma unroll
    for (int qs = 0; qs < 4; qs++) {
        l_acc4[qs] = (f32x4){0.f, 0.f, 0.f, 0.f};
#pragma unroll
        for (int vt = 0; vt < 4; vt++) Oacc[qs][vt] = (f32x4){0.f, 0.f, 0.f, 0.f};
    }

    const __bf16 one_bf = (__bf16)1.0f;
    bf16x8 vones = {one_bf, one_bf, one_bf, one_bf, one_bf, one_bf, one_bf, one_bf};

    u16* Pw = &P_lds[w][0];

    for (int kt = kt0; kt <= kt1; kt++) {
        __syncthreads();   // prev iter's LDS reads done (+ drains in-flight loads)
        *(u16x8*)(K_lds + wc0) = krA0;
        *(u16x8*)(K_lds + wc1) = krA1;
        *(u16x8*)(V_lds + wc0) = vrA0;
        *(u16x8*)(V_lds + wc1) = vrA1;
        __syncthreads();   // tile kt visible to all waves
        // Issue next tile's loads now: they overlap the whole compute phase
        // and are drained by the next iteration's first __syncthreads.
        int ktn = (kt < kt1) ? kt + 1 : kt1;
        {
            const u16* Ktn = Kp0 + (size_t)ktn * 4096;
            krA0 = *(const u16x8*)(Ktn + r0 * 64 + g0 * 8);
            krA1 = *(const u16x8*)(Ktn + r1 * 64 + g1 * 8);
            vrA0 = *(const u16x8*)(VTp + (size_t)r0 * SEQ + ktn * 64 + g0 * 8);
            vrA1 = *(const u16x8*)(VTp + (size_t)r1 * SEQ + ktn * 64 + g1 * 8);
        }

        if (kt <= qt_w) {
            // K fragments once, reused by all 4 q-subtiles.
            bf16x8 ka[4][2];
#pragma unroll
            for (int mt = 0; mt < 4; mt++) {
                int row = mt * 16 + l15;
                ka[mt][0] = *(const bf16x8*)(K_lds + row * 64 + rd0);
                ka[mt][1] = *(const bf16x8*)(K_lds + row * 64 + rd1);
            }

            bf16x8 aP[4][2];
#pragma unroll
            for (int qs = 0; qs < 4; qs++) {
                f32x4 sv[4];
#pragma unroll
                for (int mt = 0; mt < 4; mt++) {
                    f32x4 z = (f32x4){0.f, 0.f, 0.f, 0.f};
                    z = mfma_bf16(ka[mt][0], bQ[qs][0], z);
                    z = mfma_bf16(ka[mt][1], bQ[qs][1], z);
                    sv[mt] = z;
                }
                // exp2 (+ causal mask on this wave's diagonal tile), packed
                // b64 write into wave-private scratch, immediate readback.
                if (kt != qt_w) {
#pragma unroll
                    for (int mt = 0; mt < 4; mt++) {
                        uint2 t;
                        t.x = pack_bf16(__builtin_amdgcn_exp2f(sv[mt][0]),
                                        __builtin_amdgcn_exp2f(sv[mt][1]));
                        t.y = pack_bf16(__builtin_amdgcn_exp2f(sv[mt][2]),
                                        __builtin_amdgcn_exp2f(sv[mt][3]));
                        *(uint2*)(Pw + l15 * 64 + ((mt * 16 + g * 4) ^ swz)) = t;
                    }
                } else {
                    int qg = qs * 16 + l15;
#pragma unroll
                    for (int mt = 0; mt < 4; mt++) {
                        float p[4];
#pragma unroll
                        for (int r = 0; r < 4; r++) {
                            int kg = mt * 16 + g * 4 + r;
                            p[r] = (kg <= qg) ? __builtin_amdgcn_exp2f(sv[mt][r]) : 0.f;
                        }
                        uint2 t;
                        t.x = pack_bf16(p[0], p[1]);
                        t.y = pack_bf16(p[2], p[3]);
                        *(uint2*)(Pw + l15 * 64 + ((mt * 16 + g * 4) ^ swz)) = t;
                    }
                }
                aP[qs][0] = *(const bf16x8*)(Pw + l15 * 64 + rd0);
                aP[qs][1] = *(const bf16x8*)(Pw + l15 * 64 + rd1);
                l_acc4[qs] = mfma_bf16(aP[qs][0], vones, l_acc4[qs]);
                l_acc4[qs] = mfma_bf16(aP[qs][1], vones, l_acc4[qs]);
            }

            // PV: each V fragment read once, feeds all 4 q-subtiles.
#pragma unroll
            for (int vt = 0; vt < 4; vt++) {
                int vrow = vt * 16 + l15;
                bf16x8 bV0 = *(const bf16x8*)(V_lds + vrow * 64 + rd0);
                bf16x8 bV1 = *(const bf16x8*)(V_lds + vrow * 64 + rd1);
#pragma unroll
                for (int qs = 0; qs < 4; qs++) {
                    Oacc[qs][vt] = mfma_bf16(aP[qs][0], bV0, Oacc[qs][vt]);
                    Oacc[qs][vt] = mfma_bf16(aP[qs][1], bV1, Oacc[qs][vt]);
                }
            }
        }
    }

    // write partials: Onum (bf16) [slot][256q][64d] + l (fp32) [slot][256q]
    // Oacc layout: O[q = w*64 + qs*16 + g*4 + r][d = vt*16 + l15]
    u16* po = part + (size_t)idx * 16384;
#pragma unroll
    for (int qs = 0; qs < 4; qs++) {
#pragma unroll
        for (int vt = 0; vt < 4; vt++)
#pragma unroll
            for (int r = 0; r < 4; r++) {
                int q = w * 64 + qs * 16 + g * 4 + r;
                int d = vt * 16 + l15;
                po[q * 64 + d] = f2bf(Oacc[qs][vt][r]);
            }
        if (l15 == 0) {
#pragma unroll
            for (int r = 0; r < 4; r++)
                lpart[(size_t)idx * 256 + w * 64 + qs * 16 + g * 4 + r] = l_acc4[qs][r];
        }
    }
}

// combine partials -> aout bf16 [8192][512]
__global__ __launch_bounds__(256) void attn_combine_kernel(const u16* __restrict__ part,
                                                           const float* __restrict__ lpart,
                                                           u16* __restrict__ aout) {
    int bid = blockIdx.x;          // 16*64 blocks, one 64-row q-tile each
    int bh = bid >> 6;
    int qt = bid & 63;             // 64-row tile index
    int j = qt >> 2;               // 256-row block index
    int nc = (j < 8) ? 1 : 2;
    int sb = bh * NSLOT + (j < 8 ? j : 8 + (j - 8) * 2);

    int t = threadIdx.x;
    int q = t >> 2;
    int dg = (t & 3) * 16;
    int qoff = (qt & 3) * 64 + q;  // row within the 256-row slot

    float acc[16];
#pragma unroll
    for (int jj = 0; jj < 16; jj++) acc[jj] = 0.f;
    float ll = 0.f;
    for (int ci = 0; ci < nc; ci++) {
        const u16* pp = part + (size_t)(sb + ci) * 16384 + qoff * 64 + dg;
        u16x8 v0 = *(const u16x8*)pp;
        u16x8 v1 = *(const u16x8*)(pp + 8);
#pragma unroll
        for (int jj = 0; jj < 8; jj++) { acc[jj] += bf2f(v0[jj]); acc[8 + jj] += bf2f(v1[jj]); }
        ll += lpart[(size_t)(sb + ci) * 256 + qoff];
    }
    float inv = 1.f / (ll + 1e-10f);
    int b = bh >> 3, h = bh & 7;
    size_t row = (size_t)(b * SEQ + qt * 64 + q);
    u16 o[16];
#pragma unroll
    for (int jj = 0; jj < 16; jj++) o[jj] = f2bf(acc[jj] * inv);
    u16* dst = aout + row * 512 + h * 64 + dg;
    *(u16x8*)dst = *(u16x8*)o;
    *(u16x8*)(dst + 8) = *(u16x8*)(o + 8);
}

extern "C" void kernel_launch(void* const* d_in, const int* in_sizes, int n_in,
                              void* d_out, int out_size, void* d_ws, size_t ws_size,
                              hipStream_t stream) {
    const float* x    = (const float*)d_in[0];
    const float* g    = (const float*)d_in[1];
    const float* bta  = (const float*)d_in[2];
    const float* wqkv = (const float*)d_in[3];
    const float* wout = (const float*)d_in[4];
    float* out = (float*)d_out;

    char* ws = (char*)d_ws;
    size_t off = 0;
    auto alloc = [&](size_t bytes) {
        void* p = ws + off;
        off += (bytes + 255) & ~(size_t)255;
        return p;
    };
    // Footprint kept <= 46.1 MB (round-4's 54.6 MB is known-good; round-5's
    // 76 MB overran d_ws and corrupted neighboring allocations during timing).
    u16* xn    = (u16*)alloc((size_t)NTOK * DIM * 2);       // 16.78 MB; dead after gemm_qkv
    u16* wqkvT = (u16*)alloc((size_t)1536 * 1024 * 2);      //  3.15 MB
    u16* woutT = (u16*)alloc((size_t)1024 * 512 * 2);       //  1.05 MB
    u16* qb    = (u16*)alloc((size_t)NBH * SEQ * 64 * 2);   //  8.39 MB; dead after attn_partial
    u16* kb    = (u16*)alloc((size_t)NBH * SEQ * 64 * 2);   //  8.39 MB
    u16* vbT   = (u16*)alloc((size_t)NBH * SEQ * 64 * 2);   //  8.39 MB
    // Aliases (lifetimes disjoint by stream order, valid on every replay):
    u16* part  = xn;                                        // 384*32KB = 12.58 MB into xn region
    float* lpart = (float*)(xn + (size_t)NBH * NSLOT * 16384); // +0.39 MB, still < xn's 16.78 MB
    u16* aout  = qb;                                        // combine writes after attn_partial reads qb

    ln_kernel<<<NTOK, 256, 0, stream>>>(x, g, bta, xn);
    transpose_kernel<<<dim3(1536 / 32, 1024 / 32), 256, 0, stream>>>(wqkv, wqkvT, 1024, 1536);
    transpose_kernel<<<dim3(1024 / 32, 512 / 32), 256, 0, stream>>>(wout, woutT, 512, 1024);
    gemm_qkv_kernel<<<dim3(64, 12), 256, 0, stream>>>(xn, wqkvT, qb, kb, vbT);
    attn_partial_kernel<<<NBH * NSLOT, 256, 0, stream>>>(qb, kb, vbT, part, lpart);
    attn_combine_kernel<<<NBH * 64, 256, 0, stream>>>(part, lpart, aout);
    gemm_out_kernel<<<dim3(64, 8), 256, 0, stream>>>(aout, woutT, out);
}

// Round 6
// 260.409 us; speedup vs baseline: 1.0631x; 1.0033x over previous
//
#include <hip/hip_runtime.h>
#include <hip/hip_bf16.h>
#include <stdint.h>

typedef unsigned short u16;
typedef unsigned int u32;

typedef __attribute__((ext_vector_type(8))) __bf16 bf16x8;
typedef __attribute__((ext_vector_type(4))) float f32x4;
typedef __attribute__((ext_vector_type(8))) u16 u16x8;

#define DIM 1024
#define SEQ 4096
#define NTOK 8192   // b*n
#define NBH 16      // b*h
#define NSLOT 31    // per-head split-K slots over 256-row q-blocks, 16-k-tile chunks
                    // nch(j) = max(1,(j+1)>>2); sum_j nch(j) = 31; 496 blocks total

static __device__ __forceinline__ float bf2f(u16 u) {
    union { u32 u; float f; } c; c.u = ((u32)u) << 16; return c.f;
}
static __device__ __forceinline__ u16 f2bf(float f) {
    union { float f; u32 u; } c; c.f = f;
    u32 u = c.u;
    return (u16)((u + 0x7FFF + ((u >> 16) & 1)) >> 16);
}
static __device__ __forceinline__ u16 cvt_bf16(float f) {
    union { __bf16 b; u16 u; } c; c.b = (__bf16)f;  // RNE
    return c.u;
}
static __device__ __forceinline__ u32 pack_bf16(float lo, float hi) {
    return (u32)cvt_bf16(lo) | ((u32)cvt_bf16(hi) << 16);
}
static __device__ __forceinline__ f32x4 mfma_bf16(bf16x8 a, bf16x8 b, f32x4 c) {
    return __builtin_amdgcn_mfma_f32_16x16x32_bf16(a, b, c, 0, 0, 0);
}
static __device__ __forceinline__ int nch_of(int j) {  // chunks for q-block j
    int n = (j + 1) >> 2;
    return n < 1 ? 1 : n;
}

typedef const __attribute__((address_space(1))) unsigned int* gptr_t;
typedef __attribute__((address_space(3))) unsigned int* lptr_t;

// ---------------- LayerNorm: one block per token row (fp32 in, bf16 out) ----
__global__ __launch_bounds__(256) void ln_kernel(const float* __restrict__ x,
                                                 const float* __restrict__ g,
                                                 const float* __restrict__ bta,
                                                 u16* __restrict__ xn) {
    int row = blockIdx.x;
    int tid = threadIdx.x;
    float4 v = ((const float4*)(x + (size_t)row * DIM))[tid];
    float f[4] = {v.x, v.y, v.z, v.w};
    float s = 0.f, s2 = 0.f;
#pragma unroll
    for (int i = 0; i < 4; i++) { s += f[i]; s2 += f[i] * f[i]; }
#pragma unroll
    for (int m = 1; m < 64; m <<= 1) { s += __shfl_xor(s, m); s2 += __shfl_xor(s2, m); }
    __shared__ float red[8];
    int w = tid >> 6;
    if ((tid & 63) == 0) { red[w * 2] = s; red[w * 2 + 1] = s2; }
    __syncthreads();
    s  = red[0] + red[2] + red[4] + red[6];
    s2 = red[1] + red[3] + red[5] + red[7];
    float mu = s * (1.f / DIM);
    float var = s2 * (1.f / DIM) - mu * mu;
    float rstd = rsqrtf(var + 1e-5f);
    u16 o[4];
#pragma unroll
    for (int i = 0; i < 4; i++) {
        int c = tid * 4 + i;
        o[i] = f2bf((f[i] - mu) * rstd * g[c] + bta[c]);
    }
    *(uint64_t*)(xn + (size_t)row * DIM + tid * 4) = *(uint64_t*)o;
}

// ---------------- transpose src[R][C] fp32 -> dst[C][R] bf16 ----------------
__global__ __launch_bounds__(256) void transpose_kernel(const float* __restrict__ src,
                                                        u16* __restrict__ dst,
                                                        int R, int C) {
    __shared__ float t[32][33];
    int lx = threadIdx.x & 31, ly = threadIdx.x >> 5;
    int c = blockIdx.x * 32 + lx;
#pragma unroll
    for (int i = 0; i < 32; i += 8)
        t[ly + i][lx] = src[(size_t)(blockIdx.y * 32 + ly + i) * C + c];
    __syncthreads();
    int rr = blockIdx.y * 32 + lx;
#pragma unroll
    for (int i = 0; i < 32; i += 8)
        dst[(size_t)(blockIdx.x * 32 + ly + i) * R + rr] = f2bf(t[lx][ly + i]);
}

// ---------------- 128x128 MFMA GEMM core (m97-style global_load_lds) -------
template <int K>
static __device__ __forceinline__ void gemm_core(const u16* __restrict__ A,
                                                 const u16* __restrict__ B,
                                                 int rowBase, int colBase,
                                                 u16* A_lds, u16* B_lds,
                                                 f32x4 acc[4][4]) {
    int tid = threadIdx.x;
    int lane = tid & 63;
    int l15 = lane & 15, q4 = lane >> 4;
    int w = tid >> 6;
    int wm = w >> 1, wn = w & 1;
#pragma unroll
    for (int mt = 0; mt < 4; mt++)
#pragma unroll
        for (int nt = 0; nt < 4; nt++) acc[mt][nt] = (f32x4){0.f, 0.f, 0.f, 0.f};

    char* Ab = (char*)A_lds;
    char* Bb = (char*)B_lds;

    for (int k0 = 0; k0 < K; k0 += 32) {
        __syncthreads();
#pragma unroll
        for (int i = 0; i < 2; i++) {
            int c = i * 256 + tid;
            int r = c >> 2;
            int piece = (c & 3) * 8;
            const u16* gA = A + (size_t)(rowBase + r) * K + k0 + piece;
            const u16* gB = B + (size_t)(colBase + r) * K + k0 + piece;
            unsigned ldsOff = (unsigned)(i * 4096 + w * 1024);  // wave-uniform
            __builtin_amdgcn_global_load_lds((gptr_t)gA, (lptr_t)(Ab + ldsOff), 16, 0, 0);
            __builtin_amdgcn_global_load_lds((gptr_t)gB, (lptr_t)(Bb + ldsOff), 16, 0, 0);
        }
        __syncthreads();
        bf16x8 a[4], b[4];
#pragma unroll
        for (int mt = 0; mt < 4; mt++)
            a[mt] = *(const bf16x8*)(A_lds + (wm * 64 + mt * 16 + l15) * 32 + q4 * 8);
#pragma unroll
        for (int nt = 0; nt < 4; nt++)
            b[nt] = *(const bf16x8*)(B_lds + (wn * 64 + nt * 16 + l15) * 32 + q4 * 8);
#pragma unroll
        for (int mt = 0; mt < 4; mt++)
#pragma unroll
            for (int nt = 0; nt < 4; nt++)
                acc[mt][nt] = mfma_bf16(a[mt], b[nt], acc[mt][nt]);
    }
}

// QKV GEMM: q gets softmax scale pre-folded; v stored transposed [bh][d][n]
__global__ __launch_bounds__(256) void gemm_qkv_kernel(const u16* __restrict__ xn,
                                                       const u16* __restrict__ wT,
                                                       u16* __restrict__ qb,
                                                       u16* __restrict__ kb,
                                                       u16* __restrict__ vbT) {
    __shared__ u16 A_lds[128 * 32];
    __shared__ u16 B_lds[128 * 32];
    f32x4 acc[4][4];
    gemm_core<1024>(xn, wT, blockIdx.x * 128, blockIdx.y * 128, A_lds, B_lds, acc);
    int lane = threadIdx.x & 63;
    int w = threadIdx.x >> 6;
    int wm = w >> 1, wn = w & 1;
    const float SC = 0.125f * 1.44269504f;  // scale * log2(e), folded into q
#pragma unroll
    for (int mt = 0; mt < 4; mt++) {
#pragma unroll
        for (int nt = 0; nt < 4; nt++) {
#pragma unroll
            for (int r = 0; r < 4; r++) {
                int m = blockIdx.x * 128 + wm * 64 + mt * 16 + (lane >> 4) * 4 + r;
                int n = blockIdx.y * 128 + wn * 64 + nt * 16 + (lane & 15);
                int piece = n >> 9;
                int c = n & 511;
                int h = c >> 6;
                int d = c & 63;
                int bi = m >> 12;
                int nn = m & 4095;
                int bh = bi * 8 + h;
                float av = acc[mt][nt][r];
                if (piece == 0)      qb[((size_t)(bh * SEQ + nn) << 6) + d] = f2bf(av * SC);
                else if (piece == 1) kb[((size_t)(bh * SEQ + nn) << 6) + d] = f2bf(av);
                else                 vbT[((size_t)(bh * 64 + d) << 12) + nn] = f2bf(av);
            }
        }
    }
}

// Out projection GEMM -> d_out fp32
__global__ __launch_bounds__(256) void gemm_out_kernel(const u16* __restrict__ aout,
                                                       const u16* __restrict__ wT,
                                                       float* __restrict__ out) {
    __shared__ u16 A_lds[128 * 32];
    __shared__ u16 B_lds[128 * 32];
    f32x4 acc[4][4];
    gemm_core<512>(aout, wT, blockIdx.x * 128, blockIdx.y * 128, A_lds, B_lds, acc);
    int lane = threadIdx.x & 63;
    int w = threadIdx.x >> 6;
    int wm = w >> 1, wn = w & 1;
#pragma unroll
    for (int mt = 0; mt < 4; mt++) {
#pragma unroll
        for (int nt = 0; nt < 4; nt++) {
#pragma unroll
            for (int r = 0; r < 4; r++) {
                int m = blockIdx.x * 128 + wm * 64 + mt * 16 + (lane >> 4) * 4 + r;
                int n = blockIdx.y * 128 + wn * 64 + nt * 16 + (lane & 15);
                out[(size_t)m * DIM + n] = acc[mt][nt][r];
            }
        }
    }
}

// ---------------- split-K causal flash attention (no-max softmax) ----------
// Block = 4 waves, 256 q-rows (wave w owns rows w*64..w*64+63 of q-block j).
// ROUND 6: same per-wave structure as round 5 (measured VGPR=152, passing),
// only the grid changed: 16-k-tile chunks (last chunk absorbs remainder)
// -> nch(j) = max(1,(j+1)>>2), 31 slots/bh, 496 blocks (was 384). Round-5's
// 384-block grid ran at 2.2 waves/CU avg (Occupancy 6.9%) -- pure
// parallelism deficit; chunk lens now 4..28 (was 4..64) so balance + supply
// both improve. Total staging iterations per bh stay 544 (chunking splits,
// never duplicates, K/V tile loads) -> FETCH unchanged.
// Partials: 496 x 32KB + lpart = 16.76 MB, fits dead xn region (16.777 MB).

__global__ __launch_bounds__(256) void attn_partial_kernel(const u16* __restrict__ qb,
                                                           const u16* __restrict__ kb,
                                                           const u16* __restrict__ vbT,
                                                           u16* __restrict__ part,
                                                           float* __restrict__ lpart) {
    __shared__ u16 K_lds[4096];      // [64 k-rows][64 d], swizzled    8KB
    __shared__ u16 V_lds[4096];      // [64 d-rows][64 k], swizzled    8KB
    __shared__ u16 P_lds[4][1024];   // per-wave 16x64 scratch         8KB

    // XCD-aware bijective swizzle (496 = 8 * 62): each XCD keeps ~2 bh of
    // K/V hot in its private L2; big chunks dispatch first per XCD.
    int bid = blockIdx.x;
    int bs = (bid & 7) * 62 + (bid >> 3);
    int idx = NBH * NSLOT - 1 - bs;
    int bh = idx / NSLOT;
    int s  = idx - bh * NSLOT;
    // slot s -> (q-block j, chunk c): chunks of 16 k-tiles, last absorbs rem.
    int j = 0, base = 0;
    while (base + nch_of(j) <= s) { base += nch_of(j); j++; }
    int c = s - base;
    int nc = nch_of(j);
    int kt0 = c * 16;
    int kt1 = (c == nc - 1) ? (4 * j + 3) : (c * 16 + 15);

    int tid = threadIdx.x;
    int lane = tid & 63;
    int l15 = lane & 15, g = lane >> 4;
    int w = tid >> 6;
    int swz = (l15 & 7) << 3;       // read-side XOR (u16 units, 16B granules)
    int rd0 = (g * 8) ^ swz;
    int rd1 = (32 + g * 8) ^ swz;

    const u16* Kp0 = kb + (size_t)bh * SEQ * 64;
    const u16* VTp = vbT + (size_t)bh * 64 * SEQ;
    const u16* Qp  = qb + ((size_t)bh * SEQ + (size_t)j * 256 + w * 64) * 64;

    // Q fragments (B-operand) for this wave's 64 q-rows, straight from global.
    bf16x8 bQ[4][2];
#pragma unroll
    for (int qs = 0; qs < 4; qs++) {
        const u16* qp = Qp + (qs * 16 + l15) * 64 + g * 8;
        bQ[qs][0] = *(const bf16x8*)qp;
        bQ[qs][1] = *(const bf16x8*)(qp + 32);
    }

    int qt_w = j * 4 + w;           // this wave's diagonal k-tile index

    // Staging: 512 granules (16B) per 64x64 tile, 2 per thread.
    int c0 = tid, c1 = tid + 256;
    int r0 = c0 >> 3, g0 = c0 & 7;
    int r1 = c1 >> 3, g1 = c1 & 7;
    int wc0 = r0 * 64 + ((g0 ^ (r0 & 7)) * 8);   // swizzled LDS u16 index
    int wc1 = r1 * 64 + ((g1 ^ (r1 & 7)) * 8);

    // Prefetch tile kt0 into registers.
    u16x8 krA0, krA1, vrA0, vrA1;
    {
        const u16* Kt = Kp0 + (size_t)kt0 * 4096;
        krA0 = *(const u16x8*)(Kt + r0 * 64 + g0 * 8);
        krA1 = *(const u16x8*)(Kt + r1 * 64 + g1 * 8);
        vrA0 = *(const u16x8*)(VTp + (size_t)r0 * SEQ + kt0 * 64 + g0 * 8);
        vrA1 = *(const u16x8*)(VTp + (size_t)r1 * SEQ + kt0 * 64 + g1 * 8);
    }

    f32x4 Oacc[4][4];
    f32x4 l_acc4[4];
#pragma unroll
    for (int qs = 0; qs < 4; qs++) {
        l_acc4[qs] = (f32x4){0.f, 0.f, 0.f, 0.f};
#pragma unroll
        for (int vt = 0; vt < 4; vt++) Oacc[qs][vt] = (f32x4){0.f, 0.f, 0.f, 0.f};
    }

    const __bf16 one_bf = (__bf16)1.0f;
    bf16x8 vones = {one_bf, one_bf, one_bf, one_bf, one_bf, one_bf, one_bf, one_bf};

    u16* Pw = &P_lds[w][0];

    for (int kt = kt0; kt <= kt1; kt++) {
        __syncthreads();   // prev iter's LDS reads done (+ drains in-flight loads)
        *(u16x8*)(K_lds + wc0) = krA0;
        *(u16x8*)(K_lds + wc1) = krA1;
        *(u16x8*)(V_lds + wc0) = vrA0;
        *(u16x8*)(V_lds + wc1) = vrA1;
        __syncthreads();   // tile kt visible to all waves
        // Issue next tile's loads now: they overlap the whole compute phase
        // and are drained by the next iteration's first __syncthreads.
        int ktn = (kt < kt1) ? kt + 1 : kt1;
        {
            const u16* Ktn = Kp0 + (size_t)ktn * 4096;
            krA0 = *(const u16x8*)(Ktn + r0 * 64 + g0 * 8);
            krA1 = *(const u16x8*)(Ktn + r1 * 64 + g1 * 8);
            vrA0 = *(const u16x8*)(VTp + (size_t)r0 * SEQ + ktn * 64 + g0 * 8);
            vrA1 = *(const u16x8*)(VTp + (size_t)r1 * SEQ + ktn * 64 + g1 * 8);
        }

        if (kt <= qt_w) {
            // K fragments once, reused by all 4 q-subtiles.
            bf16x8 ka[4][2];
#pragma unroll
            for (int mt = 0; mt < 4; mt++) {
                int row = mt * 16 + l15;
                ka[mt][0] = *(const bf16x8*)(K_lds + row * 64 + rd0);
                ka[mt][1] = *(const bf16x8*)(K_lds + row * 64 + rd1);
            }

            bf16x8 aP[4][2];
#pragma unroll
            for (int qs = 0; qs < 4; qs++) {
                f32x4 sv[4];
#pragma unroll
                for (int mt = 0; mt < 4; mt++) {
                    f32x4 z = (f32x4){0.f, 0.f, 0.f, 0.f};
                    z = mfma_bf16(ka[mt][0], bQ[qs][0], z);
                    z = mfma_bf16(ka[mt][1], bQ[qs][1], z);
                    sv[mt] = z;
                }
                // exp2 (+ causal mask on this wave's diagonal tile), packed
                // b64 write into wave-private scratch, immediate readback.
                if (kt != qt_w) {
#pragma unroll
                    for (int mt = 0; mt < 4; mt++) {
                        uint2 t;
                        t.x = pack_bf16(__builtin_amdgcn_exp2f(sv[mt][0]),
                                        __builtin_amdgcn_exp2f(sv[mt][1]));
                        t.y = pack_bf16(__builtin_amdgcn_exp2f(sv[mt][2]),
                                        __builtin_amdgcn_exp2f(sv[mt][3]));
                        *(uint2*)(Pw + l15 * 64 + ((mt * 16 + g * 4) ^ swz)) = t;
                    }
                } else {
                    int qg = qs * 16 + l15;
#pragma unroll
                    for (int mt = 0; mt < 4; mt++) {
                        float p[4];
#pragma unroll
                        for (int r = 0; r < 4; r++) {
                            int kg = mt * 16 + g * 4 + r;
                            p[r] = (kg <= qg) ? __builtin_amdgcn_exp2f(sv[mt][r]) : 0.f;
                        }
                        uint2 t;
                        t.x = pack_bf16(p[0], p[1]);
                        t.y = pack_bf16(p[2], p[3]);
                        *(uint2*)(Pw + l15 * 64 + ((mt * 16 + g * 4) ^ swz)) = t;
                    }
                }
                aP[qs][0] = *(const bf16x8*)(Pw + l15 * 64 + rd0);
                aP[qs][1] = *(const bf16x8*)(Pw + l15 * 64 + rd1);
                l_acc4[qs] = mfma_bf16(aP[qs][0], vones, l_acc4[qs]);
                l_acc4[qs] = mfma_bf16(aP[qs][1], vones, l_acc4[qs]);
            }

            // PV: each V fragment read once, feeds all 4 q-subtiles.
#pragma unroll
            for (int vt = 0; vt < 4; vt++) {
                int vrow = vt * 16 + l15;
                bf16x8 bV0 = *(const bf16x8*)(V_lds + vrow * 64 + rd0);
                bf16x8 bV1 = *(const bf16x8*)(V_lds + vrow * 64 + rd1);
#pragma unroll
                for (int qs = 0; qs < 4; qs++) {
                    Oacc[qs][vt] = mfma_bf16(aP[qs][0], bV0, Oacc[qs][vt]);
                    Oacc[qs][vt] = mfma_bf16(aP[qs][1], bV1, Oacc[qs][vt]);
                }
            }
        }
    }

    // write partials: Onum (bf16) [slot][256q][64d] + l (fp32) [slot][256q]
    // Oacc layout: O[q = w*64 + qs*16 + g*4 + r][d = vt*16 + l15]
    u16* po = part + (size_t)idx * 16384;
#pragma unroll
    for (int qs = 0; qs < 4; qs++) {
#pragma unroll
        for (int vt = 0; vt < 4; vt++)
#pragma unroll
            for (int r = 0; r < 4; r++) {
                int q = w * 64 + qs * 16 + g * 4 + r;
                int d = vt * 16 + l15;
                po[q * 64 + d] = f2bf(Oacc[qs][vt][r]);
            }
        if (l15 == 0) {
#pragma unroll
            for (int r = 0; r < 4; r++)
                lpart[(size_t)idx * 256 + w * 64 + qs * 16 + g * 4 + r] = l_acc4[qs][r];
        }
    }
}

// combine partials -> aout bf16 [8192][512]
__global__ __launch_bounds__(256) void attn_combine_kernel(const u16* __restrict__ part,
                                                           const float* __restrict__ lpart,
                                                           u16* __restrict__ aout) {
    int bid = blockIdx.x;          // 16*64 blocks, one 64-row q-tile each
    int bh = bid >> 6;
    int qt = bid & 63;             // 64-row tile index
    int j = qt >> 2;               // 256-row block index
    int nc = nch_of(j);
    int base = 0;
    for (int i = 0; i < j; i++) base += nch_of(i);
    int sb = bh * NSLOT + base;

    int t = threadIdx.x;
    int q = t >> 2;
    int dg = (t & 3) * 16;
    int qoff = (qt & 3) * 64 + q;  // row within the 256-row slot

    float acc[16];
#pragma unroll
    for (int jj = 0; jj < 16; jj++) acc[jj] = 0.f;
    float ll = 0.f;
    for (int ci = 0; ci < nc; ci++) {
        const u16* pp = part + (size_t)(sb + ci) * 16384 + qoff * 64 + dg;
        u16x8 v0 = *(const u16x8*)pp;
        u16x8 v1 = *(const u16x8*)(pp + 8);
#pragma unroll
        for (int jj = 0; jj < 8; jj++) { acc[jj] += bf2f(v0[jj]); acc[8 + jj] += bf2f(v1[jj]); }
        ll += lpart[(size_t)(sb + ci) * 256 + qoff];
    }
    float inv = 1.f / (ll + 1e-10f);
    int b = bh >> 3, h = bh & 7;
    size_t row = (size_t)(b * SEQ + qt * 64 + q);
    u16 o[16];
#pragma unroll
    for (int jj = 0; jj < 16; jj++) o[jj] = f2bf(acc[jj] * inv);
    u16* dst = aout + row * 512 + h * 64 + dg;
    *(u16x8*)dst = *(u16x8*)o;
    *(u16x8*)(dst + 8) = *(u16x8*)(o + 8);
}

extern "C" void kernel_launch(void* const* d_in, const int* in_sizes, int n_in,
                              void* d_out, int out_size, void* d_ws, size_t ws_size,
                              hipStream_t stream) {
    const float* x    = (const float*)d_in[0];
    const float* g    = (const float*)d_in[1];
    const float* bta  = (const float*)d_in[2];
    const float* wqkv = (const float*)d_in[3];
    const float* wout = (const float*)d_in[4];
    float* out = (float*)d_out;

    char* ws = (char*)d_ws;
    size_t off = 0;
    auto alloc = [&](size_t bytes) {
        void* p = ws + off;
        off += (bytes + 255) & ~(size_t)255;
        return p;
    };
    // Footprint kept <= 46.1 MB (known-good; 76 MB overran d_ws previously).
    u16* xn    = (u16*)alloc((size_t)NTOK * DIM * 2);       // 16.78 MB; dead after gemm_qkv
    u16* wqkvT = (u16*)alloc((size_t)1536 * 1024 * 2);      //  3.15 MB
    u16* woutT = (u16*)alloc((size_t)1024 * 512 * 2);       //  1.05 MB
    u16* qb    = (u16*)alloc((size_t)NBH * SEQ * 64 * 2);   //  8.39 MB; dead after attn_partial
    u16* kb    = (u16*)alloc((size_t)NBH * SEQ * 64 * 2);   //  8.39 MB
    u16* vbT   = (u16*)alloc((size_t)NBH * SEQ * 64 * 2);   //  8.39 MB
    // Aliases (lifetimes disjoint by stream order, valid on every replay):
    // part: 496 slots x 32KB = 16.25 MB; lpart: +0.51 MB; total 16.76 MB
    // fits inside xn's 16.777 MB region.
    u16* part  = xn;
    float* lpart = (float*)(xn + (size_t)NBH * NSLOT * 16384);
    u16* aout  = qb;                                        // combine writes after attn_partial reads qb

    ln_kernel<<<NTOK, 256, 0, stream>>>(x, g, bta, xn);
    transpose_kernel<<<dim3(1536 / 32, 1024 / 32), 256, 0, stream>>>(wqkv, wqkvT, 1024, 1536);
    transpose_kernel<<<dim3(1024 / 32, 512 / 32), 256, 0, stream>>>(wout, woutT, 512, 1024);
    gemm_qkv_kernel<<<dim3(64, 12), 256, 0, stream>>>(xn, wqkvT, qb, kb, vbT);
    attn_partial_kernel<<<NBH * NSLOT, 256, 0, stream>>>(qb, kb, vbT, part, lpart);
    attn_combine_kernel<<<NBH * 64, 256, 0, stream>>>(part, lpart, aout);
    gemm_out_kernel<<<dim3(64, 8), 256, 0, stream>>>(aout, woutT, out);
}

// Round 7
// 216.133 us; speedup vs baseline: 1.2809x; 1.2049x over previous
//
#include <hip/hip_runtime.h>
#include <hip/hip_bf16.h>
#include <stdint.h>

typedef unsigned short u16;
typedef unsigned int u32;

typedef __attribute__((ext_vector_type(8))) __bf16 bf16x8;
typedef __attribute__((ext_vector_type(4))) float f32x4;
typedef __attribute__((ext_vector_type(8))) u16 u16x8;

#define DIM 1024
#define SEQ 4096
#define NTOK 8192   // b*n
#define NBH 16      // b*h
#define NSLOT 136   // per-head split-K slots over 64-row q-tiles, balanced <=20-tile chunks
                    // nch(qt) = ceil((qt+1)/20): qt 0..19 ->1, 20..39 ->2, 40..59 ->3, 60..63 ->4

static __device__ __forceinline__ float bf2f(u16 u) {
    union { u32 u; float f; } c; c.u = ((u32)u) << 16; return c.f;
}
static __device__ __forceinline__ u16 f2bf(float f) {
    union { float f; u32 u; } c; c.f = f;
    u32 u = c.u;
    return (u16)((u + 0x7FFF + ((u >> 16) & 1)) >> 16);
}
static __device__ __forceinline__ u16 cvt_bf16(float f) {
    union { __bf16 b; u16 u; } c; c.b = (__bf16)f;  // RNE
    return c.u;
}
static __device__ __forceinline__ u32 pack_bf16(float lo, float hi) {
    return (u32)cvt_bf16(lo) | ((u32)cvt_bf16(hi) << 16);
}
static __device__ __forceinline__ f32x4 mfma_bf16(bf16x8 a, bf16x8 b, f32x4 c) {
    return __builtin_amdgcn_mfma_f32_16x16x32_bf16(a, b, c, 0, 0, 0);
}

typedef const __attribute__((address_space(1))) unsigned int* gptr_t;
typedef __attribute__((address_space(3))) unsigned int* lptr_t;

// ---------------- LayerNorm: one block per token row (fp32 in, bf16 out) ----
__global__ __launch_bounds__(256) void ln_kernel(const float* __restrict__ x,
                                                 const float* __restrict__ g,
                                                 const float* __restrict__ bta,
                                                 u16* __restrict__ xn) {
    int row = blockIdx.x;
    int tid = threadIdx.x;
    float4 v = ((const float4*)(x + (size_t)row * DIM))[tid];
    float f[4] = {v.x, v.y, v.z, v.w};
    float s = 0.f, s2 = 0.f;
#pragma unroll
    for (int i = 0; i < 4; i++) { s += f[i]; s2 += f[i] * f[i]; }
#pragma unroll
    for (int m = 1; m < 64; m <<= 1) { s += __shfl_xor(s, m); s2 += __shfl_xor(s2, m); }
    __shared__ float red[8];
    int w = tid >> 6;
    if ((tid & 63) == 0) { red[w * 2] = s; red[w * 2 + 1] = s2; }
    __syncthreads();
    s  = red[0] + red[2] + red[4] + red[6];
    s2 = red[1] + red[3] + red[5] + red[7];
    float mu = s * (1.f / DIM);
    float var = s2 * (1.f / DIM) - mu * mu;
    float rstd = rsqrtf(var + 1e-5f);
    u16 o[4];
#pragma unroll
    for (int i = 0; i < 4; i++) {
        int c = tid * 4 + i;
        o[i] = f2bf((f[i] - mu) * rstd * g[c] + bta[c]);
    }
    *(uint64_t*)(xn + (size_t)row * DIM + tid * 4) = *(uint64_t*)o;
}

// ---------------- transpose src[R][C] fp32 -> dst[C][R] bf16 ----------------
__global__ __launch_bounds__(256) void transpose_kernel(const float* __restrict__ src,
                                                        u16* __restrict__ dst,
                                                        int R, int C) {
    __shared__ float t[32][33];
    int lx = threadIdx.x & 31, ly = threadIdx.x >> 5;
    int c = blockIdx.x * 32 + lx;
#pragma unroll
    for (int i = 0; i < 32; i += 8)
        t[ly + i][lx] = src[(size_t)(blockIdx.y * 32 + ly + i) * C + c];
    __syncthreads();
    int rr = blockIdx.y * 32 + lx;
#pragma unroll
    for (int i = 0; i < 32; i += 8)
        dst[(size_t)(blockIdx.x * 32 + ly + i) * R + rr] = f2bf(t[lx][ly + i]);
}

// ---------------- 128x128 MFMA GEMM core (m97-style global_load_lds) -------
template <int K>
static __device__ __forceinline__ void gemm_core(const u16* __restrict__ A,
                                                 const u16* __restrict__ B,
                                                 int rowBase, int colBase,
                                                 u16* A_lds, u16* B_lds,
                                                 f32x4 acc[4][4]) {
    int tid = threadIdx.x;
    int lane = tid & 63;
    int l15 = lane & 15, q4 = lane >> 4;
    int w = tid >> 6;
    int wm = w >> 1, wn = w & 1;
#pragma unroll
    for (int mt = 0; mt < 4; mt++)
#pragma unroll
        for (int nt = 0; nt < 4; nt++) acc[mt][nt] = (f32x4){0.f, 0.f, 0.f, 0.f};

    char* Ab = (char*)A_lds;
    char* Bb = (char*)B_lds;

    for (int k0 = 0; k0 < K; k0 += 32) {
        __syncthreads();
#pragma unroll
        for (int i = 0; i < 2; i++) {
            int c = i * 256 + tid;
            int r = c >> 2;
            int piece = (c & 3) * 8;
            const u16* gA = A + (size_t)(rowBase + r) * K + k0 + piece;
            const u16* gB = B + (size_t)(colBase + r) * K + k0 + piece;
            unsigned ldsOff = (unsigned)(i * 4096 + w * 1024);  // wave-uniform
            __builtin_amdgcn_global_load_lds((gptr_t)gA, (lptr_t)(Ab + ldsOff), 16, 0, 0);
            __builtin_amdgcn_global_load_lds((gptr_t)gB, (lptr_t)(Bb + ldsOff), 16, 0, 0);
        }
        __syncthreads();
        bf16x8 a[4], b[4];
#pragma unroll
        for (int mt = 0; mt < 4; mt++)
            a[mt] = *(const bf16x8*)(A_lds + (wm * 64 + mt * 16 + l15) * 32 + q4 * 8);
#pragma unroll
        for (int nt = 0; nt < 4; nt++)
            b[nt] = *(const bf16x8*)(B_lds + (wn * 64 + nt * 16 + l15) * 32 + q4 * 8);
#pragma unroll
        for (int mt = 0; mt < 4; mt++)
#pragma unroll
            for (int nt = 0; nt < 4; nt++)
                acc[mt][nt] = mfma_bf16(a[mt], b[nt], acc[mt][nt]);
    }
}

// QKV GEMM: q gets softmax scale pre-folded; v stored transposed [bh][d][n]
__global__ __launch_bounds__(256) void gemm_qkv_kernel(const u16* __restrict__ xn,
                                                       const u16* __restrict__ wT,
                                                       u16* __restrict__ qb,
                                                       u16* __restrict__ kb,
                                                       u16* __restrict__ vbT) {
    __shared__ u16 A_lds[128 * 32];
    __shared__ u16 B_lds[128 * 32];
    f32x4 acc[4][4];
    gemm_core<1024>(xn, wT, blockIdx.x * 128, blockIdx.y * 128, A_lds, B_lds, acc);
    int lane = threadIdx.x & 63;
    int w = threadIdx.x >> 6;
    int wm = w >> 1, wn = w & 1;
    const float SC = 0.125f * 1.44269504f;  // scale * log2(e), folded into q
#pragma unroll
    for (int mt = 0; mt < 4; mt++) {
#pragma unroll
        for (int nt = 0; nt < 4; nt++) {
#pragma unroll
            for (int r = 0; r < 4; r++) {
                int m = blockIdx.x * 128 + wm * 64 + mt * 16 + (lane >> 4) * 4 + r;
                int n = blockIdx.y * 128 + wn * 64 + nt * 16 + (lane & 15);
                int piece = n >> 9;
                int c = n & 511;
                int h = c >> 6;
                int d = c & 63;
                int bi = m >> 12;
                int nn = m & 4095;
                int bh = bi * 8 + h;
                float av = acc[mt][nt][r];
                if (piece == 0)      qb[((size_t)(bh * SEQ + nn) << 6) + d] = f2bf(av * SC);
                else if (piece == 1) kb[((size_t)(bh * SEQ + nn) << 6) + d] = f2bf(av);
                else                 vbT[((size_t)(bh * 64 + d) << 12) + nn] = f2bf(av);
            }
        }
    }
}

// Out projection GEMM -> d_out fp32
__global__ __launch_bounds__(256) void gemm_out_kernel(const u16* __restrict__ aout,
                                                       const u16* __restrict__ wT,
                                                       float* __restrict__ out) {
    __shared__ u16 A_lds[128 * 32];
    __shared__ u16 B_lds[128 * 32];
    f32x4 acc[4][4];
    gemm_core<512>(aout, wT, blockIdx.x * 128, blockIdx.y * 128, A_lds, B_lds, acc);
    int lane = threadIdx.x & 63;
    int w = threadIdx.x >> 6;
    int wm = w >> 1, wn = w & 1;
#pragma unroll
    for (int mt = 0; mt < 4; mt++) {
#pragma unroll
        for (int nt = 0; nt < 4; nt++) {
#pragma unroll
            for (int r = 0; r < 4; r++) {
                int m = blockIdx.x * 128 + wm * 64 + mt * 16 + (lane >> 4) * 4 + r;
                int n = blockIdx.y * 128 + wn * 64 + nt * 16 + (lane & 15);
                out[(size_t)m * DIM + n] = acc[mt][nt][r];
            }
        }
    }
}

// ---------------- split-K causal flash attention (no-max softmax) ----------
// ROUND 7 = round-1's measured-best structure (87us, Occ 30%: 4 waves/block,
// 16 q-rows/wave, 64-q blocks) with three isolated fixes:
//  1. stride-64 XOR-swizzled LDS (r5/6-proven mechanics) - P b64 writes become
//     perfectly bank-balanced (round-1's ASTR=72 put them on even banks only).
//  2. Q loaded directly from global as B-fragments (r5/6-proven) - drops the
//     QP staging region and its extra barrier; LDS 27.6 -> 24 KB.
//  3. balanced split-K chunks <=20 k-tiles (lengths 10..20, not 1..32):
//     NSLOT=136, grid 2176 (= 8*272, bijective XCD swizzle) for more blocks
//     in flight and a shorter tail.
// Slot s -> (qt, ci) banding: s<20: qt=s,ci=0 | s<60: 2-chunk qts | s<120:
// 3-chunk | else 4-chunk. Chunk bounds split (qt+1) tiles evenly.

__global__ __launch_bounds__(256) void attn_partial_kernel(const u16* __restrict__ qb,
                                                           const u16* __restrict__ kb,
                                                           const u16* __restrict__ vbT,
                                                           u16* __restrict__ part,
                                                           float* __restrict__ lpart) {
    __shared__ u16 K_lds[4096];      // [64 k-rows][64 d], swizzled    8KB
    __shared__ u16 V_lds[4096];      // [64 d-rows][64 k], swizzled    8KB
    __shared__ u16 P_lds[4][1024];   // per-wave 16x64 scratch         8KB

    // XCD-aware bijective swizzle (2176 = 8 * 272).
    int bid = blockIdx.x;
    int bs = (bid & 7) * 272 + (bid >> 3);
    int idx = NBH * NSLOT - 1 - bs;
    int bh = idx / NSLOT;
    int s  = idx - bh * NSLOT;
    int qt, ci;
    if (s < 20)       { qt = s; ci = 0; }
    else if (s < 60)  { int t = s - 20;  qt = 20 + (t >> 1); ci = t & 1; }
    else if (s < 120) { int t = s - 60;  qt = 40 + t / 3;    ci = t - (t / 3) * 3; }
    else              { int t = s - 120; qt = 60 + (t >> 2); ci = t & 3; }
    int nq = qt + 1;
    int nc = (nq + 19) / 20;
    int L  = nq / nc;
    int R  = nq - L * nc;
    int kt0 = ci * L + (ci < R ? ci : R);
    int kt1 = kt0 + L + (ci < R ? 1 : 0) - 1;

    int tid = threadIdx.x;
    int lane = tid & 63;
    int l15 = lane & 15, g = lane >> 4;
    int w = tid >> 6;
    int swz = (l15 & 7) << 3;       // read-side XOR (u16 units, 16B granules)
    int rd0 = (g * 8) ^ swz;
    int rd1 = (32 + g * 8) ^ swz;

    const u16* Kp0 = kb + (size_t)bh * SEQ * 64;
    const u16* VTp = vbT + (size_t)bh * 64 * SEQ;

    // Q fragments (B-operand) for this wave's 16 q-rows, straight from global.
    const u16* qp = qb + ((size_t)bh * SEQ + (size_t)qt * 64 + w * 16 + l15) * 64;
    bf16x8 bQ0 = *(const bf16x8*)(qp + g * 8);
    bf16x8 bQ1 = *(const bf16x8*)(qp + 32 + g * 8);

    // Staging: 512 granules (16B) per 64x64 tile, 2 per thread.
    int c0 = tid, c1 = tid + 256;
    int r0 = c0 >> 3, g0 = c0 & 7;
    int r1 = c1 >> 3, g1 = c1 & 7;
    int wc0 = r0 * 64 + ((g0 ^ (r0 & 7)) * 8);   // swizzled LDS u16 index
    int wc1 = r1 * 64 + ((g1 ^ (r1 & 7)) * 8);

    // Prefetch tile kt0 into registers.
    u16x8 krA0, krA1, vrA0, vrA1;
    {
        const u16* Kt = Kp0 + (size_t)kt0 * 4096;
        krA0 = *(const u16x8*)(Kt + r0 * 64 + g0 * 8);
        krA1 = *(const u16x8*)(Kt + r1 * 64 + g1 * 8);
        vrA0 = *(const u16x8*)(VTp + (size_t)r0 * SEQ + kt0 * 64 + g0 * 8);
        vrA1 = *(const u16x8*)(VTp + (size_t)r1 * SEQ + kt0 * 64 + g1 * 8);
    }

    f32x4 Oacc[4];
    f32x4 l_acc = (f32x4){0.f, 0.f, 0.f, 0.f};
#pragma unroll
    for (int vt = 0; vt < 4; vt++) Oacc[vt] = (f32x4){0.f, 0.f, 0.f, 0.f};

    const __bf16 one_bf = (__bf16)1.0f;
    bf16x8 vones = {one_bf, one_bf, one_bf, one_bf, one_bf, one_bf, one_bf, one_bf};

    u16* Pw = &P_lds[w][0];

    for (int kt = kt0; kt <= kt1; kt++) {
        __syncthreads();   // prev iter's LDS reads done
        *(u16x8*)(K_lds + wc0) = krA0;
        *(u16x8*)(K_lds + wc1) = krA1;
        *(u16x8*)(V_lds + wc0) = vrA0;
        *(u16x8*)(V_lds + wc1) = vrA1;
        __syncthreads();   // tile kt visible to all waves
        // Issue next tile's loads now: they overlap the whole compute phase.
        int ktn = (kt < kt1) ? kt + 1 : kt1;
        {
            const u16* Ktn = Kp0 + (size_t)ktn * 4096;
            krA0 = *(const u16x8*)(Ktn + r0 * 64 + g0 * 8);
            krA1 = *(const u16x8*)(Ktn + r1 * 64 + g1 * 8);
            vrA0 = *(const u16x8*)(VTp + (size_t)r0 * SEQ + ktn * 64 + g0 * 8);
            vrA1 = *(const u16x8*)(VTp + (size_t)r1 * SEQ + ktn * 64 + g1 * 8);
        }

        // QK^T (swapped): sv[nt][r] = S[q = w*16 + l15][k = kt*64 + nt*16 + g*4 + r]
        f32x4 sv[4];
#pragma unroll
        for (int nt = 0; nt < 4; nt++) {
            int row = nt * 16 + l15;
            bf16x8 a0 = *(const bf16x8*)(K_lds + row * 64 + rd0);
            bf16x8 a1 = *(const bf16x8*)(K_lds + row * 64 + rd1);
            f32x4 z = (f32x4){0.f, 0.f, 0.f, 0.f};
            z = mfma_bf16(a0, bQ0, z);
            z = mfma_bf16(a1, bQ1, z);
            sv[nt] = z;
        }

        // exp2 (+ causal mask on the diagonal tile), packed b64 write into
        // wave-private scratch (bank-balanced under the swizzle), readback.
        if (kt != qt) {
#pragma unroll
            for (int nt = 0; nt < 4; nt++) {
                uint2 t;
                t.x = pack_bf16(__builtin_amdgcn_exp2f(sv[nt][0]),
                                __builtin_amdgcn_exp2f(sv[nt][1]));
                t.y = pack_bf16(__builtin_amdgcn_exp2f(sv[nt][2]),
                                __builtin_amdgcn_exp2f(sv[nt][3]));
                *(uint2*)(Pw + l15 * 64 + ((nt * 16 + g * 4) ^ swz)) = t;
            }
        } else {
            int qg = w * 16 + l15;
#pragma unroll
            for (int nt = 0; nt < 4; nt++) {
                float p[4];
#pragma unroll
                for (int r = 0; r < 4; r++) {
                    int kg = nt * 16 + g * 4 + r;
                    p[r] = (kg <= qg) ? __builtin_amdgcn_exp2f(sv[nt][r]) : 0.f;
                }
                uint2 t;
                t.x = pack_bf16(p[0], p[1]);
                t.y = pack_bf16(p[2], p[3]);
                *(uint2*)(Pw + l15 * 64 + ((nt * 16 + g * 4) ^ swz)) = t;
            }
        }

        // P back as A-operand: lane holds P[q = l15][kd = g*8+j].
        bf16x8 aP0 = *(const bf16x8*)(Pw + l15 * 64 + rd0);
        bf16x8 aP1 = *(const bf16x8*)(Pw + l15 * 64 + rd1);
        l_acc = mfma_bf16(aP0, vones, l_acc);   // denominator via ones-column MFMA
        l_acc = mfma_bf16(aP1, vones, l_acc);
#pragma unroll
        for (int vt = 0; vt < 4; vt++) {
            int vrow = vt * 16 + l15;
            bf16x8 bV0 = *(const bf16x8*)(V_lds + vrow * 64 + rd0);
            bf16x8 bV1 = *(const bf16x8*)(V_lds + vrow * 64 + rd1);
            Oacc[vt] = mfma_bf16(aP0, bV0, Oacc[vt]);
            Oacc[vt] = mfma_bf16(aP1, bV1, Oacc[vt]);
        }
    }

    // write partials: Onum (bf16) [slot][64q][64d] + l (fp32) [slot][64q]
    // Oacc layout: O[q = w*16 + g*4 + r][d = vt*16 + l15]
    u16* po = part + (size_t)idx * 4096;
#pragma unroll
    for (int vt = 0; vt < 4; vt++)
#pragma unroll
        for (int r = 0; r < 4; r++) {
            int q = w * 16 + g * 4 + r;
            int d = vt * 16 + l15;
            po[q * 64 + d] = f2bf(Oacc[vt][r]);
        }
    if (l15 == 0) {
#pragma unroll
        for (int r = 0; r < 4; r++)
            lpart[(size_t)idx * 64 + w * 16 + g * 4 + r] = l_acc[r];
    }
}

// combine partials -> aout bf16 [8192][512]
__global__ __launch_bounds__(256) void attn_combine_kernel(const u16* __restrict__ part,
                                                           const float* __restrict__ lpart,
                                                           u16* __restrict__ aout) {
    int bid = blockIdx.x;          // 16*64 blocks, one 64-row q-tile each
    int bh = bid >> 6;
    int qt = bid & 63;
    int nc, base;
    if (qt < 20)      { nc = 1; base = qt; }
    else if (qt < 40) { nc = 2; base = 20 + (qt - 20) * 2; }
    else if (qt < 60) { nc = 3; base = 60 + (qt - 40) * 3; }
    else              { nc = 4; base = 120 + (qt - 60) * 4; }
    int sb = bh * NSLOT + base;

    int t = threadIdx.x;
    int q = t >> 2;
    int dg = (t & 3) * 16;

    float acc[16];
#pragma unroll
    for (int j = 0; j < 16; j++) acc[j] = 0.f;
    float ll = 0.f;
    for (int ci = 0; ci < nc; ci++) {
        const u16* pp = part + (size_t)(sb + ci) * 4096 + q * 64 + dg;
        u16x8 v0 = *(const u16x8*)pp;
        u16x8 v1 = *(const u16x8*)(pp + 8);
#pragma unroll
        for (int j = 0; j < 8; j++) { acc[j] += bf2f(v0[j]); acc[8 + j] += bf2f(v1[j]); }
        ll += lpart[(size_t)(sb + ci) * 64 + q];
    }
    float inv = 1.f / (ll + 1e-10f);
    int b = bh >> 3, h = bh & 7;
    size_t row = (size_t)(b * SEQ + qt * 64 + q);
    u16 o[16];
#pragma unroll
    for (int j = 0; j < 16; j++) o[j] = f2bf(acc[j] * inv);
    u16* dst = aout + row * 512 + h * 64 + dg;
    *(u16x8*)dst = *(u16x8*)o;
    *(u16x8*)(dst + 8) = *(u16x8*)(o + 8);
}

extern "C" void kernel_launch(void* const* d_in, const int* in_sizes, int n_in,
                              void* d_out, int out_size, void* d_ws, size_t ws_size,
                              hipStream_t stream) {
    const float* x    = (const float*)d_in[0];
    const float* g    = (const float*)d_in[1];
    const float* bta  = (const float*)d_in[2];
    const float* wqkv = (const float*)d_in[3];
    const float* wout = (const float*)d_in[4];
    float* out = (float*)d_out;

    char* ws = (char*)d_ws;
    size_t off = 0;
    auto alloc = [&](size_t bytes) {
        void* p = ws + off;
        off += (bytes + 255) & ~(size_t)255;
        return p;
    };
    // Footprint kept <= 46.1 MB (known-good; 76 MB overran d_ws previously).
    u16* xn    = (u16*)alloc((size_t)NTOK * DIM * 2);       // 16.78 MB; dead after gemm_qkv
    u16* wqkvT = (u16*)alloc((size_t)1536 * 1024 * 2);      //  3.15 MB; dead after gemm_qkv
    u16* woutT = (u16*)alloc((size_t)1024 * 512 * 2);       //  1.05 MB; live until gemm_out
    u16* qb    = (u16*)alloc((size_t)NBH * SEQ * 64 * 2);   //  8.39 MB; dead after attn_partial
    u16* kb    = (u16*)alloc((size_t)NBH * SEQ * 64 * 2);   //  8.39 MB
    u16* vbT   = (u16*)alloc((size_t)NBH * SEQ * 64 * 2);   //  8.39 MB
    // Aliases (lifetimes disjoint by stream order, valid on every replay --
    // transpose re-writes wqkvT before gemm_qkv each replay):
    // part: 2176 slots x 8KB = 17.83 MB; lpart +0.56 MB; total 18.38 MB fits
    // the dead xn+wqkvT span (19.92 MB) and never touches woutT.
    u16* part  = xn;
    float* lpart = (float*)(xn + (size_t)NBH * NSLOT * 4096);
    u16* aout  = qb;                                        // combine writes after attn_partial reads qb

    ln_kernel<<<NTOK, 256, 0, stream>>>(x, g, bta, xn);
    transpose_kernel<<<dim3(1536 / 32, 1024 / 32), 256, 0, stream>>>(wqkv, wqkvT, 1024, 1536);
    transpose_kernel<<<dim3(1024 / 32, 512 / 32), 256, 0, stream>>>(wout, woutT, 512, 1024);
    gemm_qkv_kernel<<<dim3(64, 12), 256, 0, stream>>>(xn, wqkvT, qb, kb, vbT);
    attn_partial_kernel<<<NBH * NSLOT, 256, 0, stream>>>(qb, kb, vbT, part, lpart);
    attn_combine_kernel<<<NBH * 64, 256, 0, stream>>>(part, lpart, aout);
    gemm_out_kernel<<<dim3(64, 8), 256, 0, stream>>>(aout, woutT, out);
}

// Round 8
// 210.401 us; speedup vs baseline: 1.3158x; 1.0272x over previous
//
#include <hip/hip_runtime.h>
#include <hip/hip_bf16.h>
#include <stdint.h>

typedef unsigned short u16;
typedef unsigned int u32;

typedef __attribute__((ext_vector_type(8))) __bf16 bf16x8;
typedef __attribute__((ext_vector_type(4))) float f32x4;
typedef __attribute__((ext_vector_type(8))) u16 u16x8;

#define DIM 1024
#define SEQ 4096
#define NTOK 8192   // b*n
#define NBH 16      // b*h
#define NSLOT 136   // per-head split-K slots over 64-row q-tiles, balanced <=20-tile chunks
                    // nch(qt) = ceil((qt+1)/20): qt 0..19 ->1, 20..39 ->2, 40..59 ->3, 60..63 ->4

static __device__ __forceinline__ float bf2f(u16 u) {
    union { u32 u; float f; } c; c.u = ((u32)u) << 16; return c.f;
}
static __device__ __forceinline__ u16 f2bf(float f) {
    union { float f; u32 u; } c; c.f = f;
    u32 u = c.u;
    return (u16)((u + 0x7FFF + ((u >> 16) & 1)) >> 16);
}
static __device__ __forceinline__ u16 cvt_bf16(float f) {
    union { __bf16 b; u16 u; } c; c.b = (__bf16)f;  // RNE
    return c.u;
}
static __device__ __forceinline__ u32 pack_bf16(float lo, float hi) {
    return (u32)cvt_bf16(lo) | ((u32)cvt_bf16(hi) << 16);
}
static __device__ __forceinline__ f32x4 mfma_bf16(bf16x8 a, bf16x8 b, f32x4 c) {
    return __builtin_amdgcn_mfma_f32_16x16x32_bf16(a, b, c, 0, 0, 0);
}

typedef const __attribute__((address_space(1))) unsigned int* gptr_t;
typedef __attribute__((address_space(3))) unsigned int* lptr_t;

// ---------------- fused prep: LayerNorm + both weight transposes ------------
// blockIdx < NTOK:            LN row (fp32 in, bf16 out)
// NTOK   <= blockIdx < +1536: transpose wqkv [1024][1536] -> wqkvT [1536][1024]
// else (+512):                transpose wout [512][1024]  -> woutT [1024][512]
// All three are independent producers for the GEMMs; fusing saves 2 launches.
__global__ __launch_bounds__(256) void prep_kernel(const float* __restrict__ x,
                                                   const float* __restrict__ g,
                                                   const float* __restrict__ bta,
                                                   u16* __restrict__ xn,
                                                   const float* __restrict__ wqkv,
                                                   u16* __restrict__ wqkvT,
                                                   const float* __restrict__ wout,
                                                   u16* __restrict__ woutT) {
    __shared__ float red[8];
    __shared__ float tT[32][33];
    int bid = blockIdx.x;
    int tid = threadIdx.x;

    if (bid < NTOK) {
        int row = bid;
        float4 v = ((const float4*)(x + (size_t)row * DIM))[tid];
        float f[4] = {v.x, v.y, v.z, v.w};
        float s = 0.f, s2 = 0.f;
#pragma unroll
        for (int i = 0; i < 4; i++) { s += f[i]; s2 += f[i] * f[i]; }
#pragma unroll
        for (int m = 1; m < 64; m <<= 1) { s += __shfl_xor(s, m); s2 += __shfl_xor(s2, m); }
        int w = tid >> 6;
        if ((tid & 63) == 0) { red[w * 2] = s; red[w * 2 + 1] = s2; }
        __syncthreads();
        s  = red[0] + red[2] + red[4] + red[6];
        s2 = red[1] + red[3] + red[5] + red[7];
        float mu = s * (1.f / DIM);
        float var = s2 * (1.f / DIM) - mu * mu;
        float rstd = rsqrtf(var + 1e-5f);
        u16 o[4];
#pragma unroll
        for (int i = 0; i < 4; i++) {
            int c = tid * 4 + i;
            o[i] = f2bf((f[i] - mu) * rstd * g[c] + bta[c]);
        }
        *(uint64_t*)(xn + (size_t)row * DIM + tid * 4) = *(uint64_t*)o;
        return;
    }

    int tt = bid - NTOK;
    const float* src; u16* dst; int R, C, bx, by;
    if (tt < 1536) { src = wqkv; dst = wqkvT; R = 1024; C = 1536; bx = tt % 48; by = tt / 48; }
    else { tt -= 1536; src = wout; dst = woutT; R = 512; C = 1024; bx = tt & 31; by = tt >> 5; }
    int lx = tid & 31, ly = tid >> 5;
    int c = bx * 32 + lx;
#pragma unroll
    for (int i = 0; i < 32; i += 8)
        tT[ly + i][lx] = src[(size_t)(by * 32 + ly + i) * C + c];
    __syncthreads();
    int rr = by * 32 + lx;
#pragma unroll
    for (int i = 0; i < 32; i += 8)
        dst[(size_t)(bx * 32 + ly + i) * R + rr] = f2bf(tT[lx][ly + i]);
}

// ---------------- 128x128 MFMA GEMM core (m97-style global_load_lds) -------
template <int K>
static __device__ __forceinline__ void gemm_core(const u16* __restrict__ A,
                                                 const u16* __restrict__ B,
                                                 int rowBase, int colBase,
                                                 u16* A_lds, u16* B_lds,
                                                 f32x4 acc[4][4]) {
    int tid = threadIdx.x;
    int lane = tid & 63;
    int l15 = lane & 15, q4 = lane >> 4;
    int w = tid >> 6;
    int wm = w >> 1, wn = w & 1;
#pragma unroll
    for (int mt = 0; mt < 4; mt++)
#pragma unroll
        for (int nt = 0; nt < 4; nt++) acc[mt][nt] = (f32x4){0.f, 0.f, 0.f, 0.f};

    char* Ab = (char*)A_lds;
    char* Bb = (char*)B_lds;

    for (int k0 = 0; k0 < K; k0 += 32) {
        __syncthreads();
#pragma unroll
        for (int i = 0; i < 2; i++) {
            int c = i * 256 + tid;
            int r = c >> 2;
            int piece = (c & 3) * 8;
            const u16* gA = A + (size_t)(rowBase + r) * K + k0 + piece;
            const u16* gB = B + (size_t)(colBase + r) * K + k0 + piece;
            unsigned ldsOff = (unsigned)(i * 4096 + w * 1024);  // wave-uniform
            __builtin_amdgcn_global_load_lds((gptr_t)gA, (lptr_t)(Ab + ldsOff), 16, 0, 0);
            __builtin_amdgcn_global_load_lds((gptr_t)gB, (lptr_t)(Bb + ldsOff), 16, 0, 0);
        }
        __syncthreads();
        bf16x8 a[4], b[4];
#pragma unroll
        for (int mt = 0; mt < 4; mt++)
            a[mt] = *(const bf16x8*)(A_lds + (wm * 64 + mt * 16 + l15) * 32 + q4 * 8);
#pragma unroll
        for (int nt = 0; nt < 4; nt++)
            b[nt] = *(const bf16x8*)(B_lds + (wn * 64 + nt * 16 + l15) * 32 + q4 * 8);
#pragma unroll
        for (int mt = 0; mt < 4; mt++)
#pragma unroll
            for (int nt = 0; nt < 4; nt++)
                acc[mt][nt] = mfma_bf16(a[mt], b[nt], acc[mt][nt]);
    }
}

// QKV GEMM: q gets softmax scale pre-folded; v stored transposed [bh][d][n]
__global__ __launch_bounds__(256) void gemm_qkv_kernel(const u16* __restrict__ xn,
                                                       const u16* __restrict__ wT,
                                                       u16* __restrict__ qb,
                                                       u16* __restrict__ kb,
                                                       u16* __restrict__ vbT) {
    __shared__ u16 A_lds[128 * 32];
    __shared__ u16 B_lds[128 * 32];
    f32x4 acc[4][4];
    gemm_core<1024>(xn, wT, blockIdx.x * 128, blockIdx.y * 128, A_lds, B_lds, acc);
    int lane = threadIdx.x & 63;
    int w = threadIdx.x >> 6;
    int wm = w >> 1, wn = w & 1;
    const float SC = 0.125f * 1.44269504f;  // scale * log2(e), folded into q
#pragma unroll
    for (int mt = 0; mt < 4; mt++) {
#pragma unroll
        for (int nt = 0; nt < 4; nt++) {
#pragma unroll
            for (int r = 0; r < 4; r++) {
                int m = blockIdx.x * 128 + wm * 64 + mt * 16 + (lane >> 4) * 4 + r;
                int n = blockIdx.y * 128 + wn * 64 + nt * 16 + (lane & 15);
                int piece = n >> 9;
                int c = n & 511;
                int h = c >> 6;
                int d = c & 63;
                int bi = m >> 12;
                int nn = m & 4095;
                int bh = bi * 8 + h;
                float av = acc[mt][nt][r];
                if (piece == 0)      qb[((size_t)(bh * SEQ + nn) << 6) + d] = f2bf(av * SC);
                else if (piece == 1) kb[((size_t)(bh * SEQ + nn) << 6) + d] = f2bf(av);
                else                 vbT[((size_t)(bh * 64 + d) << 12) + nn] = f2bf(av);
            }
        }
    }
}

// Out projection GEMM -> d_out fp32
__global__ __launch_bounds__(256) void gemm_out_kernel(const u16* __restrict__ aout,
                                                       const u16* __restrict__ wT,
                                                       float* __restrict__ out) {
    __shared__ u16 A_lds[128 * 32];
    __shared__ u16 B_lds[128 * 32];
    f32x4 acc[4][4];
    gemm_core<512>(aout, wT, blockIdx.x * 128, blockIdx.y * 128, A_lds, B_lds, acc);
    int lane = threadIdx.x & 63;
    int w = threadIdx.x >> 6;
    int wm = w >> 1, wn = w & 1;
#pragma unroll
    for (int mt = 0; mt < 4; mt++) {
#pragma unroll
        for (int nt = 0; nt < 4; nt++) {
#pragma unroll
            for (int r = 0; r < 4; r++) {
                int m = blockIdx.x * 128 + wm * 64 + mt * 16 + (lane >> 4) * 4 + r;
                int n = blockIdx.y * 128 + wn * 64 + nt * 16 + (lane & 15);
                out[(size_t)m * DIM + n] = acc[mt][nt][r];
            }
        }
    }
}

// ---------------- split-K causal flash attention (no-max softmax) ----------
// ROUND 8 = round-7 (66us, verified) with 2x arithmetic intensity per wave:
// block = 2 WAVES (128 threads), wave w owns 32 q-rows (qs=0,1 subtiles of
// 16), same 64-row q-tile per block. Each K/V LDS fragment now feeds 2 MFMAs
// and staging amortizes over 2x work: per block-tile LDS traffic 96KB->64KB.
// Grid, slot mapping, partials layout, and combine kernel are IDENTICAL to
// round 7 (2176 blocks = 8*272, bijective XCD swizzle, chunks 10..20 tiles).
// LDS 20KB (K 8 + V 8 + P 2x2KB) -> 8-block/CU cap.

__global__ __launch_bounds__(128) void attn_partial_kernel(const u16* __restrict__ qb,
                                                           const u16* __restrict__ kb,
                                                           const u16* __restrict__ vbT,
                                                           u16* __restrict__ part,
                                                           float* __restrict__ lpart) {
    __shared__ u16 K_lds[4096];      // [64 k-rows][64 d], swizzled    8KB
    __shared__ u16 V_lds[4096];      // [64 d-rows][64 k], swizzled    8KB
    __shared__ u16 P_lds[2][1024];   // per-wave 16x64 scratch         4KB

    // XCD-aware bijective swizzle (2176 = 8 * 272).
    int bid = blockIdx.x;
    int bs = (bid & 7) * 272 + (bid >> 3);
    int idx = NBH * NSLOT - 1 - bs;
    int bh = idx / NSLOT;
    int s  = idx - bh * NSLOT;
    int qt, ci;
    if (s < 20)       { qt = s; ci = 0; }
    else if (s < 60)  { int t = s - 20;  qt = 20 + (t >> 1); ci = t & 1; }
    else if (s < 120) { int t = s - 60;  qt = 40 + t / 3;    ci = t - (t / 3) * 3; }
    else              { int t = s - 120; qt = 60 + (t >> 2); ci = t & 3; }
    int nq = qt + 1;
    int nc = (nq + 19) / 20;
    int L  = nq / nc;
    int R  = nq - L * nc;
    int kt0 = ci * L + (ci < R ? ci : R);
    int kt1 = kt0 + L + (ci < R ? 1 : 0) - 1;

    int tid = threadIdx.x;          // 0..127
    int lane = tid & 63;
    int l15 = lane & 15, g = lane >> 4;
    int w = tid >> 6;               // 0..1
    int swz = (l15 & 7) << 3;       // read-side XOR (u16 units, 16B granules)
    int rd0 = (g * 8) ^ swz;
    int rd1 = (32 + g * 8) ^ swz;

    const u16* Kp0 = kb + (size_t)bh * SEQ * 64;
    const u16* VTp = vbT + (size_t)bh * 64 * SEQ;

    // Q fragments (B-operand) for this wave's 32 q-rows, straight from global.
    bf16x8 bQ[2][2];
#pragma unroll
    for (int qs = 0; qs < 2; qs++) {
        const u16* qp = qb + ((size_t)bh * SEQ + (size_t)qt * 64 + w * 32 + qs * 16 + l15) * 64;
        bQ[qs][0] = *(const bf16x8*)(qp + g * 8);
        bQ[qs][1] = *(const bf16x8*)(qp + 32 + g * 8);
    }

    // Staging: 512 granules (16B) per 64x64 tile, 4 per thread (128 threads).
    int wcc[4], soK[4];
    size_t soV[4];
#pragma unroll
    for (int i = 0; i < 4; i++) {
        int c = tid + 128 * i;
        int r = c >> 3, gg = c & 7;
        wcc[i] = r * 64 + ((gg ^ (r & 7)) * 8);   // swizzled LDS u16 index
        soK[i] = r * 64 + gg * 8;                  // K source offset (u16)
        soV[i] = (size_t)r * SEQ + gg * 8;         // V source offset (u16), + kt*64
    }

    // Prefetch tile kt0 into registers.
    u16x8 krA[4], vrA[4];
    {
        const u16* Kt = Kp0 + (size_t)kt0 * 4096;
#pragma unroll
        for (int i = 0; i < 4; i++) {
            krA[i] = *(const u16x8*)(Kt + soK[i]);
            vrA[i] = *(const u16x8*)(VTp + soV[i] + kt0 * 64);
        }
    }

    f32x4 Oacc[2][4];
    f32x4 l_acc[2];
#pragma unroll
    for (int qs = 0; qs < 2; qs++) {
        l_acc[qs] = (f32x4){0.f, 0.f, 0.f, 0.f};
#pragma unroll
        for (int vt = 0; vt < 4; vt++) Oacc[qs][vt] = (f32x4){0.f, 0.f, 0.f, 0.f};
    }

    const __bf16 one_bf = (__bf16)1.0f;
    bf16x8 vones = {one_bf, one_bf, one_bf, one_bf, one_bf, one_bf, one_bf, one_bf};

    u16* Pw = &P_lds[w][0];

    for (int kt = kt0; kt <= kt1; kt++) {
        __syncthreads();   // prev iter's LDS reads done
#pragma unroll
        for (int i = 0; i < 4; i++) {
            *(u16x8*)(K_lds + wcc[i]) = krA[i];
            *(u16x8*)(V_lds + wcc[i]) = vrA[i];
        }
        __syncthreads();   // tile kt visible to both waves
        // Issue next tile's loads now: they overlap the whole compute phase.
        int ktn = (kt < kt1) ? kt + 1 : kt1;
        {
            const u16* Ktn = Kp0 + (size_t)ktn * 4096;
#pragma unroll
            for (int i = 0; i < 4; i++) {
                krA[i] = *(const u16x8*)(Ktn + soK[i]);
                vrA[i] = *(const u16x8*)(VTp + soV[i] + ktn * 64);
            }
        }

        // K fragments once, reused by both q-subtiles.
        bf16x8 ka[4][2];
#pragma unroll
        for (int nt = 0; nt < 4; nt++) {
            int row = nt * 16 + l15;
            ka[nt][0] = *(const bf16x8*)(K_lds + row * 64 + rd0);
            ka[nt][1] = *(const bf16x8*)(K_lds + row * 64 + rd1);
        }

        bf16x8 aP[2][2];
#pragma unroll
        for (int qs = 0; qs < 2; qs++) {
            // QK^T (swapped): sv[nt][r] = S[q = w*32+qs*16+l15][k = kt*64+nt*16+g*4+r]
            f32x4 sv[4];
#pragma unroll
            for (int nt = 0; nt < 4; nt++) {
                f32x4 z = (f32x4){0.f, 0.f, 0.f, 0.f};
                z = mfma_bf16(ka[nt][0], bQ[qs][0], z);
                z = mfma_bf16(ka[nt][1], bQ[qs][1], z);
                sv[nt] = z;
            }

            // exp2 (+ causal mask on the diagonal tile), packed b64 write into
            // wave-private scratch (bank-balanced under the swizzle), readback.
            if (kt != qt) {
#pragma unroll
                for (int nt = 0; nt < 4; nt++) {
                    uint2 t;
                    t.x = pack_bf16(__builtin_amdgcn_exp2f(sv[nt][0]),
                                    __builtin_amdgcn_exp2f(sv[nt][1]));
                    t.y = pack_bf16(__builtin_amdgcn_exp2f(sv[nt][2]),
                                    __builtin_amdgcn_exp2f(sv[nt][3]));
                    *(uint2*)(Pw + l15 * 64 + ((nt * 16 + g * 4) ^ swz)) = t;
                }
            } else {
                int qg = w * 32 + qs * 16 + l15;
#pragma unroll
                for (int nt = 0; nt < 4; nt++) {
                    float p[4];
#pragma unroll
                    for (int r = 0; r < 4; r++) {
                        int kg = nt * 16 + g * 4 + r;
                        p[r] = (kg <= qg) ? __builtin_amdgcn_exp2f(sv[nt][r]) : 0.f;
                    }
                    uint2 t;
                    t.x = pack_bf16(p[0], p[1]);
                    t.y = pack_bf16(p[2], p[3]);
                    *(uint2*)(Pw + l15 * 64 + ((nt * 16 + g * 4) ^ swz)) = t;
                }
            }

            // P back as A-operand: lane holds P[q = l15][kd = g*8+j].
            aP[qs][0] = *(const bf16x8*)(Pw + l15 * 64 + rd0);
            aP[qs][1] = *(const bf16x8*)(Pw + l15 * 64 + rd1);
            l_acc[qs] = mfma_bf16(aP[qs][0], vones, l_acc[qs]);   // denominator
            l_acc[qs] = mfma_bf16(aP[qs][1], vones, l_acc[qs]);
        }

        // PV: each V fragment read once, feeds both q-subtiles.
#pragma unroll
        for (int vt = 0; vt < 4; vt++) {
            int vrow = vt * 16 + l15;
            bf16x8 bV0 = *(const bf16x8*)(V_lds + vrow * 64 + rd0);
            bf16x8 bV1 = *(const bf16x8*)(V_lds + vrow * 64 + rd1);
#pragma unroll
            for (int qs = 0; qs < 2; qs++) {
                Oacc[qs][vt] = mfma_bf16(aP[qs][0], bV0, Oacc[qs][vt]);
                Oacc[qs][vt] = mfma_bf16(aP[qs][1], bV1, Oacc[qs][vt]);
            }
        }
    }

    // write partials: Onum (bf16) [slot][64q][64d] + l (fp32) [slot][64q]
    // Oacc layout: O[q = w*32 + qs*16 + g*4 + r][d = vt*16 + l15]
    u16* po = part + (size_t)idx * 4096;
#pragma unroll
    for (int qs = 0; qs < 2; qs++) {
#pragma unroll
        for (int vt = 0; vt < 4; vt++)
#pragma unroll
            for (int r = 0; r < 4; r++) {
                int q = w * 32 + qs * 16 + g * 4 + r;
                int d = vt * 16 + l15;
                po[q * 64 + d] = f2bf(Oacc[qs][vt][r]);
            }
        if (l15 == 0) {
#pragma unroll
            for (int r = 0; r < 4; r++)
                lpart[(size_t)idx * 64 + w * 32 + qs * 16 + g * 4 + r] = l_acc[qs][r];
        }
    }
}

// combine partials -> aout bf16 [8192][512]
__global__ __launch_bounds__(256) void attn_combine_kernel(const u16* __restrict__ part,
                                                           const float* __restrict__ lpart,
                                                           u16* __restrict__ aout) {
    int bid = blockIdx.x;          // 16*64 blocks, one 64-row q-tile each
    int bh = bid >> 6;
    int qt = bid & 63;
    int nc, base;
    if (qt < 20)      { nc = 1; base = qt; }
    else if (qt < 40) { nc = 2; base = 20 + (qt - 20) * 2; }
    else if (qt < 60) { nc = 3; base = 60 + (qt - 40) * 3; }
    else              { nc = 4; base = 120 + (qt - 60) * 4; }
    int sb = bh * NSLOT + base;

    int t = threadIdx.x;
    int q = t >> 2;
    int dg = (t & 3) * 16;

    float acc[16];
#pragma unroll
    for (int j = 0; j < 16; j++) acc[j] = 0.f;
    float ll = 0.f;
    for (int ci = 0; ci < nc; ci++) {
        const u16* pp = part + (size_t)(sb + ci) * 4096 + q * 64 + dg;
        u16x8 v0 = *(const u16x8*)pp;
        u16x8 v1 = *(const u16x8*)(pp + 8);
#pragma unroll
        for (int j = 0; j < 8; j++) { acc[j] += bf2f(v0[j]); acc[8 + j] += bf2f(v1[j]); }
        ll += lpart[(size_t)(sb + ci) * 64 + q];
    }
    float inv = 1.f / (ll + 1e-10f);
    int b = bh >> 3, h = bh & 7;
    size_t row = (size_t)(b * SEQ + qt * 64 + q);
    u16 o[16];
#pragma unroll
    for (int j = 0; j < 16; j++) o[j] = f2bf(acc[j] * inv);
    u16* dst = aout + row * 512 + h * 64 + dg;
    *(u16x8*)dst = *(u16x8*)o;
    *(u16x8*)(dst + 8) = *(u16x8*)(o + 8);
}

extern "C" void kernel_launch(void* const* d_in, const int* in_sizes, int n_in,
                              void* d_out, int out_size, void* d_ws, size_t ws_size,
                              hipStream_t stream) {
    const float* x    = (const float*)d_in[0];
    const float* g    = (const float*)d_in[1];
    const float* bta  = (const float*)d_in[2];
    const float* wqkv = (const float*)d_in[3];
    const float* wout = (const float*)d_in[4];
    float* out = (float*)d_out;

    char* ws = (char*)d_ws;
    size_t off = 0;
    auto alloc = [&](size_t bytes) {
        void* p = ws + off;
        off += (bytes + 255) & ~(size_t)255;
        return p;
    };
    // Footprint kept <= 46.1 MB (known-good; 76 MB overran d_ws previously).
    u16* xn    = (u16*)alloc((size_t)NTOK * DIM * 2);       // 16.78 MB; dead after gemm_qkv
    u16* wqkvT = (u16*)alloc((size_t)1536 * 1024 * 2);      //  3.15 MB; dead after gemm_qkv
    u16* woutT = (u16*)alloc((size_t)1024 * 512 * 2);       //  1.05 MB; live until gemm_out
    u16* qb    = (u16*)alloc((size_t)NBH * SEQ * 64 * 2);   //  8.39 MB; dead after attn_partial
    u16* kb    = (u16*)alloc((size_t)NBH * SEQ * 64 * 2);   //  8.39 MB
    u16* vbT   = (u16*)alloc((size_t)NBH * SEQ * 64 * 2);   //  8.39 MB
    // Aliases (lifetimes disjoint by stream order, valid on every replay --
    // prep re-writes wqkvT before gemm_qkv each replay):
    // part: 2176 slots x 8KB = 17.83 MB; lpart +0.56 MB; total 18.38 MB fits
    // the dead xn+wqkvT span (19.92 MB) and never touches woutT.
    u16* part  = xn;
    float* lpart = (float*)(xn + (size_t)NBH * NSLOT * 4096);
    u16* aout  = qb;                                        // combine writes after attn_partial reads qb

    prep_kernel<<<NTOK + 1536 + 512, 256, 0, stream>>>(x, g, bta, xn, wqkv, wqkvT, wout, woutT);
    gemm_qkv_kernel<<<dim3(64, 12), 256, 0, stream>>>(xn, wqkvT, qb, kb, vbT);
    attn_partial_kernel<<<NBH * NSLOT, 128, 0, stream>>>(qb, kb, vbT, part, lpart);
    attn_combine_kernel<<<NBH * 64, 256, 0, stream>>>(part, lpart, aout);
    gemm_out_kernel<<<dim3(64, 8), 256, 0, stream>>>(aout, woutT, out);
}